// Round 25
// baseline (127.178 us; speedup 1.0000x reference)
//
#include <hip/hip_runtime.h>
#include <hip/hip_bf16.h>

#define NUM_HEADS 16
#define HEAD_DIM  64
#define HIDDEN    1024
#define BATCH     2
#define SEQ       2048
#define K_DIM     1024
#define INV_NORM  0.125f
#define LOG2E     1.4426950408889634f
#define IN2       (INV_NORM * LOG2E)

typedef __attribute__((ext_vector_type(4)))  float f32x4;
typedef __attribute__((ext_vector_type(16))) float f32x16;
typedef __attribute__((ext_vector_type(8)))  short bf16x8;
typedef __attribute__((ext_vector_type(4)))  unsigned int u32x4;
typedef __attribute__((ext_vector_type(2)))  unsigned int u32x2;
typedef unsigned short u16;

__device__ inline u16 f2bf(float f) {
    __hip_bfloat16 h = __float2bfloat16(f);
    return __builtin_bit_cast(u16, h);
}
__device__ inline float bf2f(u16 u) {
    unsigned int v = ((unsigned int)u) << 16;
    return __builtin_bit_cast(float, v);
}

__device__ inline f32x16 mfma32(bf16x8 a, bf16x8 b, f32x16 c) {
    return __builtin_amdgcn_mfma_f32_32x32x16_bf16(a, b, c, 0, 0, 0);
}

// async global->LDS, 16B per lane (used by gemm_dense only)
__device__ inline void gl_lds16(const u16* g, u16* s) {
    __builtin_amdgcn_global_load_lds(
        (const __attribute__((address_space(1))) unsigned int*)g,
        (__attribute__((address_space(3))) unsigned int*)s, 16, 0, 0);
}

// ---------------- cvt + pack: x,W_qkv -> fragment-major bf16; W_dense -> row-major ----------------
__device__ inline void pack8(const float* src, u16* dst) {
    const float4 v0 = *reinterpret_cast<const float4*>(src);
    const float4 v1 = *reinterpret_cast<const float4*>(src + 4);
    ushort4 o0, o1;
    o0.x = f2bf(v0.x); o0.y = f2bf(v0.y); o0.z = f2bf(v0.z); o0.w = f2bf(v0.w);
    o1.x = f2bf(v1.x); o1.y = f2bf(v1.y); o1.z = f2bf(v1.z); o1.w = f2bf(v1.w);
    *reinterpret_cast<ushort4*>(dst)     = o0;
    *reinterpret_cast<ushort4*>(dst + 4) = o1;
}
__global__ __launch_bounds__(256) void cvt_all(
        const float* __restrict__ x, const float* __restrict__ wq,
        const float* __restrict__ wd,
        u16* __restrict__ xb, u16* __restrict__ wqb, u16* __restrict__ wdb) {
    int t = blockIdx.x * 256 + threadIdx.x;   // 1048576 threads, 8 elem each
    if (t < 524288) {            // x: 4096 rows -> 128 m-tiles
        int mt = t >> 12, rem = t & 4095;
        int kblk = rem >> 6, hf = (rem >> 5) & 1, ra = rem & 31;
        pack8(x + ((size_t)(mt * 32 + ra)) * K_DIM + kblk * 16 + hf * 8,
              xb + (size_t)t * 8);
    } else if (t < 917504) {     // W_qkv: 3072 rows -> 96 tiles
        int t2 = t - 524288;
        int nt = t2 >> 12, rem = t2 & 4095;
        int kblk = rem >> 6, hf = (rem >> 5) & 1, ra = rem & 31;
        pack8(wq + ((size_t)(nt * 32 + ra)) * K_DIM + kblk * 16 + hf * 8,
              wqb + (size_t)t2 * 8);
    } else {                     // W_dense: plain row-major
        int i = (t - 917504) * 8;
        pack8(wd + i, wdb + i);
    }
}

// ---------------- QKV GEMM: LDS-free, fragment-major direct loads ----------------
#define QLOAD(P, kb) {                                                        \
    P##x0 = *reinterpret_cast<const bf16x8*>(pa0 + (size_t)(kb) * 512);       \
    P##x1 = *reinterpret_cast<const bf16x8*>(pa1 + (size_t)(kb) * 512);       \
    P##y0 = *reinterpret_cast<const bf16x8*>(pb0 + (size_t)(kb) * 512);       \
    P##y1 = *reinterpret_cast<const bf16x8*>(pb1 + (size_t)(kb) * 512);       \
    P##x2 = *reinterpret_cast<const bf16x8*>(pa0 + (size_t)(kb + 1) * 512);   \
    P##x3 = *reinterpret_cast<const bf16x8*>(pa1 + (size_t)(kb + 1) * 512);   \
    P##y2 = *reinterpret_cast<const bf16x8*>(pb0 + (size_t)(kb + 1) * 512);   \
    P##y3 = *reinterpret_cast<const bf16x8*>(pb1 + (size_t)(kb + 1) * 512);   \
}
#define QSTEP(P) {                                                            \
    acc[0][0] = mfma32(P##x0, P##y0, acc[0][0]);                              \
    acc[0][1] = mfma32(P##x0, P##y1, acc[0][1]);                              \
    acc[1][0] = mfma32(P##x1, P##y0, acc[1][0]);                              \
    acc[1][1] = mfma32(P##x1, P##y1, acc[1][1]);                              \
    acc[0][0] = mfma32(P##x2, P##y2, acc[0][0]);                              \
    acc[0][1] = mfma32(P##x2, P##y3, acc[0][1]);                              \
    acc[1][0] = mfma32(P##x3, P##y2, acc[1][0]);                              \
    acc[1][1] = mfma32(P##x3, P##y3, acc[1][1]);                              \
}
__global__ __launch_bounds__(256) void gemm_qkv(
        const u16* __restrict__ Af, const u16* __restrict__ Bf,
        const float* __restrict__ bias,
        u16* __restrict__ qo, u16* __restrict__ ko2, u16* __restrict__ vTo) {
    int lin = blockIdx.x;
    int g = lin & 7, i2 = lin >> 3;           // i2: 0..95
    const int mblk = ((g & 3) * 8 + (i2 & 7)) * 128;
    const int nblk = ((g >> 2) * 12 + (i2 >> 3)) * 128;
    const int tid = threadIdx.x;
    const int w = tid >> 6, lane = tid & 63;
    const int la = lane & 31, hi = lane >> 5;
    const int wr = w >> 1, wc = w & 1;
    const int mt0 = (mblk >> 5) + wr * 2;
    const int nt0 = (nblk >> 5) + wc * 2;
    const u16* pa0 = Af + (size_t)mt0 * 64 * 512 + lane * 8;
    const u16* pa1 = pa0 + 64 * 512;
    const u16* pb0 = Bf + (size_t)nt0 * 64 * 512 + lane * 8;
    const u16* pb1 = pb0 + 64 * 512;
    f32x16 acc[2][2] = {};
    bf16x8 ax0, ax1, ax2, ax3, ay0, ay1, ay2, ay3;
    bf16x8 bx0, bx1, bx2, bx3, by0, by1, by2, by3;
    QLOAD(a, 0)
    #pragma unroll 4
    for (int kb = 0; kb < 64; kb += 4) {
        const int n1 = (kb + 2 < 62) ? kb + 2 : 62;
        QLOAD(b, n1)
        QSTEP(a)
        const int n2 = (kb + 4 < 62) ? kb + 4 : 62;
        QLOAD(a, n2)
        QSTEP(b)
    }
    #pragma unroll
    for (int mi = 0; mi < 2; ++mi)
    #pragma unroll
    for (int ni = 0; ni < 2; ++ni) {
        int c = nblk + wc * 64 + ni * 32 + la;   // fused col: h*192 + which*64 + d
        int h = c / 192, rem = c - h * 192;
        int which = rem >> 6, d = rem & 63;
        float bv = bias[c];
        #pragma unroll
        for (int r = 0; r < 16; ++r) {
            int m = mblk + wr * 64 + mi * 32 + (r & 3) + 8 * (r >> 2) + 4 * hi;
            int bb = m >> 11, s = m & (SEQ - 1);
            int bh = bb * NUM_HEADS + h;
            int t = s >> 5;
            size_t tb = ((size_t)(bh * 64 + t)) * 2048;
            u16 o = f2bf(acc[mi][ni][r] + bv);
            if (which == 2) {
                int dblk = d >> 5, ra = d & 31;
                int k = s & 31, ks = k >> 4, hf = (k >> 3) & 1, e = k & 7;
                vTo[tb + (dblk * 2 + ks) * 512 + hf * 256 + ra * 8 + e] = o;
            } else {
                int kk = d >> 4, hf = (d >> 3) & 1, e = d & 7, ra = s & 31;
                size_t off = tb + kk * 512 + hf * 256 + ra * 8 + e;
                if (which == 0) qo[off] = o;
                else            ko2[off] = o;
            }
        }
    }
}

// ---------------- Dense GEMM + bias + residual: 64x128 tile, 512 blocks (2/CU) ----------------
__global__ __launch_bounds__(256) void gemm_dense(
        const u16* __restrict__ A, const u16* __restrict__ W,
        const float* __restrict__ bias, const float* __restrict__ residual,
        float* __restrict__ out) {
    __shared__ u16 As[64 * 64];
    __shared__ u16 Bs[128 * 64];
    int lin = blockIdx.x;
    int g = lin & 7, i2 = lin >> 3;           // i2: 0..63
    const int mblk = (g * 8 + (i2 & 7)) * 64;
    const int nblk = (i2 >> 3) * 128;
    const int tid = threadIdx.x;
    const int w = tid >> 6, l = tid & 63;
    const int la = l & 31, hi = l >> 5;
    const int wr = w & 1, wc = w >> 1;
    const int kperm = (((l & 7) ^ (l >> 3)) << 3);
    const u16* gA = A + (size_t)(mblk + w * 16 + (l >> 3)) * K_DIM + kperm;
    const u16* gB = W + (size_t)(nblk + w * 32 + (l >> 3)) * K_DIM + kperm;
    const int sca = (la & 7) << 3;
    f32x16 acc2[2] = {};
    for (int kt = 0; kt < 16; ++kt) {
        const int ko = kt * 64;
        gl_lds16(gA + ko,              &As[(w * 16) * 64]);
        gl_lds16(gA + ko + 8 * K_DIM,  &As[(w * 16 + 8) * 64]);
        #pragma unroll
        for (int i = 0; i < 4; ++i)
            gl_lds16(gB + i * 8 * K_DIM + ko, &Bs[(w * 32 + i * 8) * 64]);
        asm volatile("s_waitcnt vmcnt(0)" ::: "memory");
        __syncthreads();
        const u16* pA = &As[(wr * 32 + la) * 64];
        const u16* pB = &Bs[(wc * 64 + la) * 64];
        #pragma unroll
        for (int kk = 0; kk < 4; ++kk) {
            const int co = (kk * 16 + hi * 8) ^ sca;
            bf16x8 a0 = *reinterpret_cast<const bf16x8*>(pA + co);
            bf16x8 b0 = *reinterpret_cast<const bf16x8*>(pB + co);
            bf16x8 b1 = *reinterpret_cast<const bf16x8*>(pB + 32 * 64 + co);
            acc2[0] = mfma32(a0, b0, acc2[0]);
            acc2[1] = mfma32(a0, b1, acc2[1]);
        }
        __syncthreads();
    }
    #pragma unroll
    for (int ni = 0; ni < 2; ++ni) {
        int c = nblk + wc * 64 + ni * 32 + la;
        float bv = bias[c];
        #pragma unroll
        for (int r = 0; r < 16; ++r) {
            int m = mblk + wr * 32 + (r & 3) + 8 * (r >> 2) + 4 * hi;
            out[(size_t)m * HIDDEN + c] = acc2[ni][r] + bv + residual[(size_t)m * HIDDEN + c];
        }
    }
}

// ---------------- norms: per-(bh,slice) max ||k|| partials + per-(bh,qt) max ||q|| ----------------
__global__ __launch_bounds__(256) void norms(
        const u16* __restrict__ Kf, const u16* __restrict__ Qf,
        float* __restrict__ knp, float* __restrict__ qn,
        unsigned int* __restrict__ ctr) {
    if (blockIdx.x == 0 && threadIdx.x < 8) ctr[threadIdx.x] = 0;  // stream-ordered
    __shared__ float red[256];
    const int bh = blockIdx.x >> 3;
    const int s  = (blockIdx.x & 7) * 256 + threadIdx.x;    // one row per thread
    const size_t tb = ((size_t)(bh * 64 + (s >> 5))) * 2048 + (s & 31) * 8;
    float ssk = 0.f, ssq = 0.f;
    #pragma unroll
    for (int kk = 0; kk < 4; ++kk)
    #pragma unroll
    for (int hf = 0; hf < 2; ++hf) {
        bf16x8 v = *reinterpret_cast<const bf16x8*>(Kf + tb + kk * 512 + hf * 256);
        bf16x8 u = *reinterpret_cast<const bf16x8*>(Qf + tb + kk * 512 + hf * 256);
        #pragma unroll
        for (int e = 0; e < 8; ++e) {
            float fk = bf2f((u16)v[e]);
            float fq = bf2f((u16)u[e]);
            ssk = fmaf(fk, fk, ssk);
            ssq = fmaf(fq, fq, ssq);
        }
    }
    float mq = ssq;
    #pragma unroll
    for (int off = 1; off <= 16; off <<= 1) mq = fmaxf(mq, __shfl_xor(mq, off));
    if ((threadIdx.x & 31) == 0)
        qn[(size_t)bh * 64 + (s >> 5)] = sqrtf(mq);
    red[threadIdx.x] = ssk;
    __syncthreads();
    for (int off = 128; off; off >>= 1) {
        if (threadIdx.x < (unsigned)off)
            red[threadIdx.x] = fmaxf(red[threadIdx.x], red[threadIdx.x + off]);
        __syncthreads();
    }
    if (threadIdx.x == 0) knp[blockIdx.x] = sqrtf(red[0]);
}

// ---------------- Flash attention: VGPR/LDS diet -> 5 blocks/CU, 5 waves/SIMD ----------------
// 2-buffer ping-pong; cl[] array folded into 2xfma with inline-const cst
// (C0 = slope2*(4hi-la)-kb per item); vbase = kbase + const offset; two-pass
// combine halves o_l LDS to ~17KB.
#define LOADT(P, tt) {                                                        \
    const u16* kp_ = kbase + (size_t)(tt) * 2048;                             \
    P##k0 = *reinterpret_cast<const bf16x8*>(kp_);                            \
    P##k1 = *reinterpret_cast<const bf16x8*>(kp_ + 512);                      \
    P##k2 = *reinterpret_cast<const bf16x8*>(kp_ + 1024);                     \
    P##k3 = *reinterpret_cast<const bf16x8*>(kp_ + 1536);                     \
    const u16* vp_ = kp_ + 4194304;                                           \
    P##v0 = *reinterpret_cast<const bf16x8*>(vp_);                            \
    P##v1 = *reinterpret_cast<const bf16x8*>(vp_ + 512);                      \
    P##v2 = *reinterpret_cast<const bf16x8*>(vp_ + 1024);                     \
    P##v3 = *reinterpret_cast<const bf16x8*>(vp_ + 1536);                     \
}

#define STEP(P, N, tcur, tnxt, DIAG) {                                        \
    f32x16 sca_ = {}, scb_ = {};                                              \
    sca_ = mfma32(P##k0, qf0, sca_);                                          \
    scb_ = mfma32(P##k1, qf1, scb_);                                          \
    sca_ = mfma32(P##k2, qf2, sca_);                                          \
    scb_ = mfma32(P##k3, qf3, scb_);                                          \
    LOADT(N, tnxt)                                                            \
    const float base_ = fmaf(slope2, (float)((tcur) * 32 - qw), C0);          \
    float p[16];                                                              \
    _Pragma("unroll")                                                         \
    for (int r = 0; r < 16; ++r) {                                            \
        const float cst_ = (float)((r & 3) + 8 * (r >> 2));                   \
        p[r] = __builtin_amdgcn_exp2f(                                        \
            fmaf(sca_[r] + scb_[r], IN2, fmaf(cst_, slope2, base_)));         \
    }                                                                         \
    if (DIAG) {                                                               \
        _Pragma("unroll")                                                     \
        for (int r = 0; r < 16; ++r) {                                        \
            int kr_ = (r & 3) + 8 * (r >> 2) + 4 * hi;                        \
            if (kr_ > la) p[r] = 0.f;                                         \
        }                                                                     \
    }                                                                         \
    l_i += ((p[0] + p[1]) + (p[2] + p[3])) + ((p[4] + p[5]) + (p[6] + p[7]))  \
         + ((p[8] + p[9]) + (p[10] + p[11])) + ((p[12] + p[13]) + (p[14] + p[15])); \
    unsigned pk_[8];                                                          \
    _Pragma("unroll")                                                         \
    for (int m = 0; m < 4; ++m) {                                             \
        unsigned b0_ = __builtin_bit_cast(unsigned, p[4 * m])     + 0x8000u;  \
        unsigned b1_ = __builtin_bit_cast(unsigned, p[4 * m + 1]) + 0x8000u;  \
        unsigned b2_ = __builtin_bit_cast(unsigned, p[4 * m + 2]) + 0x8000u;  \
        unsigned b3_ = __builtin_bit_cast(unsigned, p[4 * m + 3]) + 0x8000u;  \
        pk_[2 * m]     = __builtin_amdgcn_perm(b1_, b0_, 0x07060302u);        \
        pk_[2 * m + 1] = __builtin_amdgcn_perm(b3_, b2_, 0x07060302u);        \
    }                                                                         \
    u32x2 r0_ = __builtin_amdgcn_permlane32_swap(pk_[0], pk_[2], false, false); \
    u32x2 r1_ = __builtin_amdgcn_permlane32_swap(pk_[1], pk_[3], false, false); \
    u32x2 r2_ = __builtin_amdgcn_permlane32_swap(pk_[4], pk_[6], false, false); \
    u32x2 r3_ = __builtin_amdgcn_permlane32_swap(pk_[5], pk_[7], false, false); \
    u32x4 pb0_, pb1_;                                                         \
    pb0_[0] = r0_[0]; pb0_[1] = r1_[0]; pb0_[2] = r0_[1]; pb0_[3] = r1_[1];   \
    pb1_[0] = r2_[0]; pb1_[1] = r3_[0]; pb1_[2] = r2_[1]; pb1_[3] = r3_[1];   \
    bf16x8 pf0_ = __builtin_bit_cast(bf16x8, pb0_);                           \
    bf16x8 pf1_ = __builtin_bit_cast(bf16x8, pb1_);                           \
    o0 = mfma32(P##v0, pf0_, o0);                                             \
    o0 = mfma32(P##v1, pf1_, o0);                                             \
    o1 = mfma32(P##v2, pf0_, o1);                                             \
    o1 = mfma32(P##v3, pf1_, o1);                                             \
}

__global__ __launch_bounds__(256) void attn(
        const u16* __restrict__ Qf, const u16* __restrict__ Kf,
        const u16* __restrict__ Vf, const float* __restrict__ alibi,
        const float* __restrict__ knp, const float* __restrict__ qn,
        u16* __restrict__ ctx, unsigned int* __restrict__ ctr) {
    __shared__ float o_l[4][32][33];   // half-width: two-pass combine
    __shared__ float ml[4][32];
    __shared__ unsigned int s_idx;
    const int grp  = blockIdx.x & 7;
    const int lst  = grp >> 1;
    const int bat  = grp & 1;
    const unsigned long long LH = (lst == 0) ? 0x0000000007080Full
                               : (lst == 1) ? 0x000000000006090Eull
                               : (lst == 2) ? 0x0000000003050A0Dull
                                            : 0x00000102040B0Cull;
    const unsigned nit = (lst == 0) ? 192u : (lst == 3) ? 320u : 256u;
    const int wave = __builtin_amdgcn_readfirstlane(threadIdx.x >> 6);  // SGPR
    const int lane = threadIdx.x & 63;
    const int la = lane & 31, hi = lane >> 5;

    for (;;) {
        if (threadIdx.x == 0) s_idx = atomicAdd(ctr + grp, 1u);
        __syncthreads();                     // publish s_idx; protect o_l reuse
        const unsigned int idx = s_idx;
        if (idx >= nit) return;
        const int h  = (int)((LH >> (8 * (idx >> 6))) & 0xFF);
        const int qt = 63 - (int)(idx & 63);
        const int bh = bat * 16 + h;
        const int qw = qt * 32;
        const size_t tbh = (size_t)bh * 64;
        const float slope2 = alibi[(size_t)bh * SEQ + 1] * LOG2E;

        const u16* qp = Qf + (tbh + qt) * 2048 + lane * 8;
        bf16x8 qf0 = *reinterpret_cast<const bf16x8*>(qp);
        bf16x8 qf1 = *reinterpret_cast<const bf16x8*>(qp + 512);
        bf16x8 qf2 = *reinterpret_cast<const bf16x8*>(qp + 1024);
        bf16x8 qf3 = *reinterpret_cast<const bf16x8*>(qp + 1536);

        // hoisted first-tile K/V load (t0 clamped; wasted if t0<t_lo, safe)
        const u16* kbase = Kf + tbh * 2048 + lane * 8;
        const int t0 = qt - wave;
        const int ta = (t0 >= 0) ? t0 : 0;
        bf16x8 ak0, ak1, ak2, ak3, av0, av1, av2, av3;
        bf16x8 bk0, bk1, bk2, bk3, bv0, bv1, bv2, bv3;
        LOADT(a, ta)

        // kb from precomputed norms
        const float* kp8 = knp + bh * 8;
        const float knv = fmaxf(fmaxf(fmaxf(kp8[0], kp8[1]), fmaxf(kp8[2], kp8[3])),
                                fmaxf(fmaxf(kp8[4], kp8[5]), fmaxf(kp8[6], kp8[7])));
        const float kb = qn[tbh + qt] * knv * IN2;
        const float C0 = fmaf(slope2, (float)(4 * hi - la), -kb);

        // static window: tail/L < 2^-36 beyond W = (47 + 2kb)/slope2 keys
        const float Wf = (47.f + 2.f * kb) / slope2;
        const int lo_k = qw - 31 - (int)Wf;
        const int t_lo = lo_k <= 0 ? 0 : ((lo_k + 31) >> 5);

        f32x16 o0 = {}, o1 = {};
        float l_i = 0.f;

        if (t0 >= t_lo) {
            const int nit2 = ((t0 - t_lo) >> 2) + 1;
            {   // peeled iteration 0 (diagonal only for wave 0)
                const int tn1 = (nit2 > 1) ? t0 - 4 : t0;
                if (wave == 0) { STEP(a, b, t0, tn1, 1) }
                else           { STEP(a, b, t0, tn1, 0) }
            }
            int i = 1;
            while (i < nit2) {
                {
                    const int tc = t0 - 4 * i;
                    const int tn = (i + 1 < nit2) ? tc - 4 : tc;
                    STEP(b, a, tc, tn, 0)
                }
                ++i;
                if (i >= nit2) break;
                {
                    const int tc = t0 - 4 * i;
                    const int tn = (i + 1 < nit2) ? tc - 4 : tc;
                    STEP(a, b, tc, tn, 0)
                }
                ++i;
            }
        }

        // ---- two-pass combine (plain sums; shared static M) ----
        l_i += __shfl_xor(l_i, 32);
        if (hi == 0) ml[wave][la] = l_i;
        #pragma unroll
        for (int r = 0; r < 16; ++r)
            o_l[wave][(r & 3) + 8 * (r >> 2) + 4 * hi][la] = o0[r];
        __syncthreads();
        const int qq = threadIdx.x >> 3;
        const int ds = (threadIdx.x & 7) * 4;
        const float L = ml[0][qq] + ml[1][qq] + ml[2][qq] + ml[3][qq];
        const float inv = 1.0f / L;
        const int bb = bh >> 4, hh = bh & 15;
        u16* crow = &ctx[((size_t)(bb * SEQ + qw + qq)) * HIDDEN + hh * HEAD_DIM];
        {
            u32x2 pv;
            #pragma unroll
            for (int e2 = 0; e2 < 2; ++e2) {
                float Oa = o_l[0][ds + 2 * e2][qq] + o_l[1][ds + 2 * e2][qq]
                         + o_l[2][ds + 2 * e2][qq] + o_l[3][ds + 2 * e2][qq];
                float Ob = o_l[0][ds + 2 * e2 + 1][qq] + o_l[1][ds + 2 * e2 + 1][qq]
                         + o_l[2][ds + 2 * e2 + 1][qq] + o_l[3][ds + 2 * e2 + 1][qq];
                pv[e2] = (unsigned)f2bf(Oa * inv) | ((unsigned)f2bf(Ob * inv) << 16);
            }
            *reinterpret_cast<u32x2*>(crow + ds) = pv;
        }
        __syncthreads();
        #pragma unroll
        for (int r = 0; r < 16; ++r)
            o_l[wave][(r & 3) + 8 * (r >> 2) + 4 * hi][la] = o1[r];
        __syncthreads();
        {
            u32x2 pv;
            #pragma unroll
            for (int e2 = 0; e2 < 2; ++e2) {
                float Oa = o_l[0][ds + 2 * e2][qq] + o_l[1][ds + 2 * e2][qq]
                         + o_l[2][ds + 2 * e2][qq] + o_l[3][ds + 2 * e2][qq];
                float Ob = o_l[0][ds + 2 * e2 + 1][qq] + o_l[1][ds + 2 * e2 + 1][qq]
                         + o_l[2][ds + 2 * e2 + 1][qq] + o_l[3][ds + 2 * e2 + 1][qq];
                pv[e2] = (unsigned)f2bf(Oa * inv) | ((unsigned)f2bf(Ob * inv) << 16);
            }
            *reinterpret_cast<u32x2*>(crow + 32 + ds) = pv;
        }
    }
}

extern "C" void kernel_launch(void* const* d_in, const int* in_sizes, int n_in,
                              void* d_out, int out_size, void* d_ws, size_t ws_size,
                              hipStream_t stream) {
    const float* x        = (const float*)d_in[0];
    const float* residual = (const float*)d_in[1];
    const float* alibi    = (const float*)d_in[2];
    const float* W_qkv    = (const float*)d_in[4];
    const float* b_qkv    = (const float*)d_in[5];
    const float* W_dense  = (const float*)d_in[6];
    const float* b_dense  = (const float*)d_in[7];
    float* out = (float*)d_out;

    char* ws = (char*)d_ws;
    u16* xb  = (u16*)(ws);                 //  8 MB  x bf16 fragment-major
    u16* wqb = (u16*)(ws + 8388608);       //  6 MB  W_qkv bf16 fragment-major
    u16* wdb = (u16*)(ws + 14680064);      //  2 MB  W_dense bf16 row-major
    u16* q   = (u16*)(ws + 16777216);      //  8 MB  fragment-major Q tiles
    u16* k   = (u16*)(ws + 25165824);      //  8 MB  fragment-major K tiles
    u16* vT  = (u16*)(ws + 33554432);      //  8 MB  fragment-major V tiles (k + 4194304 elems)
    u16* ctx = (u16*)(ws + 41943040);      //  8 MB  [B*S][1024]
    float* knp = (float*)(ws + 50331648);  //  1 KB  per-(bh,slice) max ||k||
    float* qn  = (float*)(ws + 50331648 + 1024);   // 8 KB per-(bh,qt) max ||q||
    unsigned int* ctr = (unsigned int*)(ws + 50331648 + 16384);  // 8 group counters

    cvt_all<<<4096, 256, 0, stream>>>(x, W_qkv, W_dense, xb, wqb, wdb);
    gemm_qkv<<<768, 256, 0, stream>>>(xb, wqb, b_qkv, q, k, vT);
    norms<<<256, 256, 0, stream>>>(k, q, knp, qn, ctr);
    attn<<<1280, 256, 0, stream>>>(q, k, vT, alibi, knp, qn, ctx, ctr);
    gemm_dense<<<512, 256, 0, stream>>>(ctx, wdb, b_dense, residual, out);
}

// Round 26
// 121.883 us; speedup vs baseline: 1.0434x; 1.0434x over previous
//
#include <hip/hip_runtime.h>
#include <hip/hip_bf16.h>

#define NUM_HEADS 16
#define HEAD_DIM  64
#define HIDDEN    1024
#define BATCH     2
#define SEQ       2048
#define K_DIM     1024
#define INV_NORM  0.125f
#define LOG2E     1.4426950408889634f
#define IN2       (INV_NORM * LOG2E)

typedef __attribute__((ext_vector_type(4)))  float f32x4;
typedef __attribute__((ext_vector_type(16))) float f32x16;
typedef __attribute__((ext_vector_type(8)))  short bf16x8;
typedef __attribute__((ext_vector_type(4)))  unsigned int u32x4;
typedef __attribute__((ext_vector_type(2)))  unsigned int u32x2;
typedef unsigned short u16;

__device__ inline u16 f2bf(float f) {
    __hip_bfloat16 h = __float2bfloat16(f);
    return __builtin_bit_cast(u16, h);
}
__device__ inline float bf2f(u16 u) {
    unsigned int v = ((unsigned int)u) << 16;
    return __builtin_bit_cast(float, v);
}

__device__ inline f32x16 mfma32(bf16x8 a, bf16x8 b, f32x16 c) {
    return __builtin_amdgcn_mfma_f32_32x32x16_bf16(a, b, c, 0, 0, 0);
}

// async global->LDS, 16B per lane (used by gemm_dense only)
__device__ inline void gl_lds16(const u16* g, u16* s) {
    __builtin_amdgcn_global_load_lds(
        (const __attribute__((address_space(1))) unsigned int*)g,
        (__attribute__((address_space(3))) unsigned int*)s, 16, 0, 0);
}

// ---------------- cvt + pack: x,W_qkv -> fragment-major bf16; W_dense -> row-major ----------------
__device__ inline void pack8(const float* src, u16* dst) {
    const float4 v0 = *reinterpret_cast<const float4*>(src);
    const float4 v1 = *reinterpret_cast<const float4*>(src + 4);
    ushort4 o0, o1;
    o0.x = f2bf(v0.x); o0.y = f2bf(v0.y); o0.z = f2bf(v0.z); o0.w = f2bf(v0.w);
    o1.x = f2bf(v1.x); o1.y = f2bf(v1.y); o1.z = f2bf(v1.z); o1.w = f2bf(v1.w);
    *reinterpret_cast<ushort4*>(dst)     = o0;
    *reinterpret_cast<ushort4*>(dst + 4) = o1;
}
__global__ __launch_bounds__(256) void cvt_all(
        const float* __restrict__ x, const float* __restrict__ wq,
        const float* __restrict__ wd,
        u16* __restrict__ xb, u16* __restrict__ wqb, u16* __restrict__ wdb) {
    int t = blockIdx.x * 256 + threadIdx.x;   // 1048576 threads, 8 elem each
    if (t < 524288) {            // x: 4096 rows -> 128 m-tiles
        int mt = t >> 12, rem = t & 4095;
        int kblk = rem >> 6, hf = (rem >> 5) & 1, ra = rem & 31;
        pack8(x + ((size_t)(mt * 32 + ra)) * K_DIM + kblk * 16 + hf * 8,
              xb + (size_t)t * 8);
    } else if (t < 917504) {     // W_qkv: 3072 rows -> 96 tiles
        int t2 = t - 524288;
        int nt = t2 >> 12, rem = t2 & 4095;
        int kblk = rem >> 6, hf = (rem >> 5) & 1, ra = rem & 31;
        pack8(wq + ((size_t)(nt * 32 + ra)) * K_DIM + kblk * 16 + hf * 8,
              wqb + (size_t)t2 * 8);
    } else {                     // W_dense: plain row-major
        int i = (t - 917504) * 8;
        pack8(wd + i, wdb + i);
    }
}

// ---------------- QKV GEMM: LDS-free, fragment-major direct loads ----------------
#define QLOAD(P, kb) {                                                        \
    P##x0 = *reinterpret_cast<const bf16x8*>(pa0 + (size_t)(kb) * 512);       \
    P##x1 = *reinterpret_cast<const bf16x8*>(pa1 + (size_t)(kb) * 512);       \
    P##y0 = *reinterpret_cast<const bf16x8*>(pb0 + (size_t)(kb) * 512);       \
    P##y1 = *reinterpret_cast<const bf16x8*>(pb1 + (size_t)(kb) * 512);       \
    P##x2 = *reinterpret_cast<const bf16x8*>(pa0 + (size_t)(kb + 1) * 512);   \
    P##x3 = *reinterpret_cast<const bf16x8*>(pa1 + (size_t)(kb + 1) * 512);   \
    P##y2 = *reinterpret_cast<const bf16x8*>(pb0 + (size_t)(kb + 1) * 512);   \
    P##y3 = *reinterpret_cast<const bf16x8*>(pb1 + (size_t)(kb + 1) * 512);   \
}
#define QSTEP(P) {                                                            \
    acc[0][0] = mfma32(P##x0, P##y0, acc[0][0]);                              \
    acc[0][1] = mfma32(P##x0, P##y1, acc[0][1]);                              \
    acc[1][0] = mfma32(P##x1, P##y0, acc[1][0]);                              \
    acc[1][1] = mfma32(P##x1, P##y1, acc[1][1]);                              \
    acc[0][0] = mfma32(P##x2, P##y2, acc[0][0]);                              \
    acc[0][1] = mfma32(P##x2, P##y3, acc[0][1]);                              \
    acc[1][0] = mfma32(P##x3, P##y2, acc[1][0]);                              \
    acc[1][1] = mfma32(P##x3, P##y3, acc[1][1]);                              \
}
__global__ __launch_bounds__(256) void gemm_qkv(
        const u16* __restrict__ Af, const u16* __restrict__ Bf,
        const float* __restrict__ bias,
        u16* __restrict__ qo, u16* __restrict__ ko2, u16* __restrict__ vTo) {
    int lin = blockIdx.x;
    int g = lin & 7, i2 = lin >> 3;           // i2: 0..95
    const int mblk = ((g & 3) * 8 + (i2 & 7)) * 128;
    const int nblk = ((g >> 2) * 12 + (i2 >> 3)) * 128;
    const int tid = threadIdx.x;
    const int w = tid >> 6, lane = tid & 63;
    const int la = lane & 31, hi = lane >> 5;
    const int wr = w >> 1, wc = w & 1;
    const int mt0 = (mblk >> 5) + wr * 2;
    const int nt0 = (nblk >> 5) + wc * 2;
    const u16* pa0 = Af + (size_t)mt0 * 64 * 512 + lane * 8;
    const u16* pa1 = pa0 + 64 * 512;
    const u16* pb0 = Bf + (size_t)nt0 * 64 * 512 + lane * 8;
    const u16* pb1 = pb0 + 64 * 512;
    f32x16 acc[2][2] = {};
    bf16x8 ax0, ax1, ax2, ax3, ay0, ay1, ay2, ay3;
    bf16x8 bx0, bx1, bx2, bx3, by0, by1, by2, by3;
    QLOAD(a, 0)
    #pragma unroll 4
    for (int kb = 0; kb < 64; kb += 4) {
        const int n1 = (kb + 2 < 62) ? kb + 2 : 62;
        QLOAD(b, n1)
        QSTEP(a)
        const int n2 = (kb + 4 < 62) ? kb + 4 : 62;
        QLOAD(a, n2)
        QSTEP(b)
    }
    #pragma unroll
    for (int mi = 0; mi < 2; ++mi)
    #pragma unroll
    for (int ni = 0; ni < 2; ++ni) {
        int c = nblk + wc * 64 + ni * 32 + la;   // fused col: h*192 + which*64 + d
        int h = c / 192, rem = c - h * 192;
        int which = rem >> 6, d = rem & 63;
        float bv = bias[c];
        #pragma unroll
        for (int r = 0; r < 16; ++r) {
            int m = mblk + wr * 64 + mi * 32 + (r & 3) + 8 * (r >> 2) + 4 * hi;
            int bb = m >> 11, s = m & (SEQ - 1);
            int bh = bb * NUM_HEADS + h;
            int t = s >> 5;
            size_t tb = ((size_t)(bh * 64 + t)) * 2048;
            u16 o = f2bf(acc[mi][ni][r] + bv);
            if (which == 2) {
                int dblk = d >> 5, ra = d & 31;
                int k = s & 31, ks = k >> 4, hf = (k >> 3) & 1, e = k & 7;
                vTo[tb + (dblk * 2 + ks) * 512 + hf * 256 + ra * 8 + e] = o;
            } else {
                int kk = d >> 4, hf = (d >> 3) & 1, e = d & 7, ra = s & 31;
                size_t off = tb + kk * 512 + hf * 256 + ra * 8 + e;
                if (which == 0) qo[off] = o;
                else            ko2[off] = o;
            }
        }
    }
}

// ---------------- Dense GEMM + bias + residual: 64x128 tile, 512 blocks (2/CU) ----------------
__global__ __launch_bounds__(256) void gemm_dense(
        const u16* __restrict__ A, const u16* __restrict__ W,
        const float* __restrict__ bias, const float* __restrict__ residual,
        float* __restrict__ out) {
    __shared__ u16 As[64 * 64];
    __shared__ u16 Bs[128 * 64];
    int lin = blockIdx.x;
    int g = lin & 7, i2 = lin >> 3;           // i2: 0..63
    const int mblk = (g * 8 + (i2 & 7)) * 64;
    const int nblk = (i2 >> 3) * 128;
    const int tid = threadIdx.x;
    const int w = tid >> 6, l = tid & 63;
    const int la = l & 31, hi = l >> 5;
    const int wr = w & 1, wc = w >> 1;
    const int kperm = (((l & 7) ^ (l >> 3)) << 3);
    const u16* gA = A + (size_t)(mblk + w * 16 + (l >> 3)) * K_DIM + kperm;
    const u16* gB = W + (size_t)(nblk + w * 32 + (l >> 3)) * K_DIM + kperm;
    const int sca = (la & 7) << 3;
    f32x16 acc2[2] = {};
    for (int kt = 0; kt < 16; ++kt) {
        const int ko = kt * 64;
        gl_lds16(gA + ko,              &As[(w * 16) * 64]);
        gl_lds16(gA + ko + 8 * K_DIM,  &As[(w * 16 + 8) * 64]);
        #pragma unroll
        for (int i = 0; i < 4; ++i)
            gl_lds16(gB + i * 8 * K_DIM + ko, &Bs[(w * 32 + i * 8) * 64]);
        asm volatile("s_waitcnt vmcnt(0)" ::: "memory");
        __syncthreads();
        const u16* pA = &As[(wr * 32 + la) * 64];
        const u16* pB = &Bs[(wc * 64 + la) * 64];
        #pragma unroll
        for (int kk = 0; kk < 4; ++kk) {
            const int co = (kk * 16 + hi * 8) ^ sca;
            bf16x8 a0 = *reinterpret_cast<const bf16x8*>(pA + co);
            bf16x8 b0 = *reinterpret_cast<const bf16x8*>(pB + co);
            bf16x8 b1 = *reinterpret_cast<const bf16x8*>(pB + 32 * 64 + co);
            acc2[0] = mfma32(a0, b0, acc2[0]);
            acc2[1] = mfma32(a0, b1, acc2[1]);
        }
        __syncthreads();
    }
    #pragma unroll
    for (int ni = 0; ni < 2; ++ni) {
        int c = nblk + wc * 64 + ni * 32 + la;
        float bv = bias[c];
        #pragma unroll
        for (int r = 0; r < 16; ++r) {
            int m = mblk + wr * 32 + (r & 3) + 8 * (r >> 2) + 4 * hi;
            out[(size_t)m * HIDDEN + c] = acc2[ni][r] + bv + residual[(size_t)m * HIDDEN + c];
        }
    }
}

// ---------------- norms: per-(bh,slice) max ||k|| partials + per-(bh,qt) max ||q|| ----------------
__global__ __launch_bounds__(256) void norms(
        const u16* __restrict__ Kf, const u16* __restrict__ Qf,
        float* __restrict__ knp, float* __restrict__ qn,
        unsigned int* __restrict__ ctr) {
    if (blockIdx.x == 0 && threadIdx.x < 8) ctr[threadIdx.x] = 0;  // stream-ordered
    __shared__ float red[256];
    const int bh = blockIdx.x >> 3;
    const int s  = (blockIdx.x & 7) * 256 + threadIdx.x;    // one row per thread
    const size_t tb = ((size_t)(bh * 64 + (s >> 5))) * 2048 + (s & 31) * 8;
    float ssk = 0.f, ssq = 0.f;
    #pragma unroll
    for (int kk = 0; kk < 4; ++kk)
    #pragma unroll
    for (int hf = 0; hf < 2; ++hf) {
        bf16x8 v = *reinterpret_cast<const bf16x8*>(Kf + tb + kk * 512 + hf * 256);
        bf16x8 u = *reinterpret_cast<const bf16x8*>(Qf + tb + kk * 512 + hf * 256);
        #pragma unroll
        for (int e = 0; e < 8; ++e) {
            float fk = bf2f((u16)v[e]);
            float fq = bf2f((u16)u[e]);
            ssk = fmaf(fk, fk, ssk);
            ssq = fmaf(fq, fq, ssq);
        }
    }
    float mq = ssq;
    #pragma unroll
    for (int off = 1; off <= 16; off <<= 1) mq = fmaxf(mq, __shfl_xor(mq, off));
    if ((threadIdx.x & 31) == 0)
        qn[(size_t)bh * 64 + (s >> 5)] = sqrtf(mq);
    red[threadIdx.x] = ssk;
    __syncthreads();
    for (int off = 128; off; off >>= 1) {
        if (threadIdx.x < (unsigned)off)
            red[threadIdx.x] = fmaxf(red[threadIdx.x], red[threadIdx.x + off]);
        __syncthreads();
    }
    if (threadIdx.x == 0) knp[blockIdx.x] = sqrtf(red[0]);
}

// ---------------- Flash attention: static-max + balanced queues + precomputed norms ----------------
#define LOADT(P, tt) {                                                        \
    const u16* kp_ = kbase + (size_t)(tt) * 2048;                             \
    P##k0 = *reinterpret_cast<const bf16x8*>(kp_);                            \
    P##k1 = *reinterpret_cast<const bf16x8*>(kp_ + 512);                      \
    P##k2 = *reinterpret_cast<const bf16x8*>(kp_ + 1024);                     \
    P##k3 = *reinterpret_cast<const bf16x8*>(kp_ + 1536);                     \
    const u16* vp_ = vbase + (size_t)(tt) * 2048;                             \
    P##v0 = *reinterpret_cast<const bf16x8*>(vp_);                            \
    P##v1 = *reinterpret_cast<const bf16x8*>(vp_ + 512);                      \
    P##v2 = *reinterpret_cast<const bf16x8*>(vp_ + 1024);                     \
    P##v3 = *reinterpret_cast<const bf16x8*>(vp_ + 1536);                     \
}

#define STEP(P, N, tcur, tnxt, DIAG) {                                        \
    f32x16 sca_ = {}, scb_ = {};                                              \
    sca_ = mfma32(P##k0, qf0, sca_);                                          \
    scb_ = mfma32(P##k1, qf1, scb_);                                          \
    sca_ = mfma32(P##k2, qf2, sca_);                                          \
    scb_ = mfma32(P##k3, qf3, scb_);                                          \
    LOADT(N, tnxt)                                                            \
    const float Dt_ = slope2 * (float)((tcur) * 32 - qw);                     \
    float p[16];                                                              \
    _Pragma("unroll")                                                         \
    for (int r = 0; r < 16; ++r)                                              \
        p[r] = __builtin_amdgcn_exp2f(fmaf(sca_[r] + scb_[r], IN2, cl[r] + Dt_)); \
    if (DIAG) {                                                               \
        _Pragma("unroll")                                                     \
        for (int r = 0; r < 16; ++r) {                                        \
            int kr_ = (r & 3) + 8 * (r >> 2) + 4 * hi;                        \
            if (kr_ > la) p[r] = 0.f;                                         \
        }                                                                     \
    }                                                                         \
    l_i += ((p[0] + p[1]) + (p[2] + p[3])) + ((p[4] + p[5]) + (p[6] + p[7]))  \
         + ((p[8] + p[9]) + (p[10] + p[11])) + ((p[12] + p[13]) + (p[14] + p[15])); \
    unsigned pk_[8];                                                          \
    _Pragma("unroll")                                                         \
    for (int m = 0; m < 4; ++m) {                                             \
        unsigned b0_ = __builtin_bit_cast(unsigned, p[4 * m])     + 0x8000u;  \
        unsigned b1_ = __builtin_bit_cast(unsigned, p[4 * m + 1]) + 0x8000u;  \
        unsigned b2_ = __builtin_bit_cast(unsigned, p[4 * m + 2]) + 0x8000u;  \
        unsigned b3_ = __builtin_bit_cast(unsigned, p[4 * m + 3]) + 0x8000u;  \
        pk_[2 * m]     = __builtin_amdgcn_perm(b1_, b0_, 0x07060302u);        \
        pk_[2 * m + 1] = __builtin_amdgcn_perm(b3_, b2_, 0x07060302u);        \
    }                                                                         \
    u32x2 r0_ = __builtin_amdgcn_permlane32_swap(pk_[0], pk_[2], false, false); \
    u32x2 r1_ = __builtin_amdgcn_permlane32_swap(pk_[1], pk_[3], false, false); \
    u32x2 r2_ = __builtin_amdgcn_permlane32_swap(pk_[4], pk_[6], false, false); \
    u32x2 r3_ = __builtin_amdgcn_permlane32_swap(pk_[5], pk_[7], false, false); \
    u32x4 pb0_, pb1_;                                                         \
    pb0_[0] = r0_[0]; pb0_[1] = r1_[0]; pb0_[2] = r0_[1]; pb0_[3] = r1_[1];   \
    pb1_[0] = r2_[0]; pb1_[1] = r3_[0]; pb1_[2] = r2_[1]; pb1_[3] = r3_[1];   \
    bf16x8 pf0_ = __builtin_bit_cast(bf16x8, pb0_);                           \
    bf16x8 pf1_ = __builtin_bit_cast(bf16x8, pb1_);                           \
    o0 = mfma32(P##v0, pf0_, o0);                                             \
    o0 = mfma32(P##v1, pf1_, o0);                                             \
    o1 = mfma32(P##v2, pf0_, o1);                                             \
    o1 = mfma32(P##v3, pf1_, o1);                                             \
}

__global__ __launch_bounds__(256) void attn(
        const u16* __restrict__ Qf, const u16* __restrict__ Kf,
        const u16* __restrict__ Vf, const float* __restrict__ alibi,
        const float* __restrict__ knp, const float* __restrict__ qn,
        u16* __restrict__ ctx, unsigned int* __restrict__ ctr) {
    __shared__ float o_l[4][64][33];
    __shared__ float ml[4][32];
    __shared__ unsigned int s_idx;
    const int grp  = blockIdx.x & 7;
    const int lst  = grp >> 1;
    const int bat  = grp & 1;
    // packed bh-head lists (byte j = head of slot j) and item counts
    const unsigned long long LH = (lst == 0) ? 0x0000000007080Full
                               : (lst == 1) ? 0x000000000006090Eull
                               : (lst == 2) ? 0x0000000003050A0Dull
                                            : 0x00000102040B0Cull;
    const unsigned nit = (lst == 0) ? 192u : (lst == 3) ? 320u : 256u;
    const int wave = __builtin_amdgcn_readfirstlane(threadIdx.x >> 6);  // SGPR
    const int lane = threadIdx.x & 63;
    const int la = lane & 31, hi = lane >> 5;

    for (;;) {
        if (threadIdx.x == 0) s_idx = atomicAdd(ctr + grp, 1u);
        __syncthreads();                     // publish s_idx; protect o_l reuse
        const unsigned int idx = s_idx;
        if (idx >= nit) return;
        const int h  = (int)((LH >> (8 * (idx >> 6))) & 0xFF);
        const int qt = 63 - (int)(idx & 63);
        const int bh = bat * 16 + h;
        const int qw = qt * 32;
        const size_t tbh = (size_t)bh * 64;
        const float slope2 = alibi[(size_t)bh * SEQ + 1] * LOG2E;

        const u16* qp = Qf + (tbh + qt) * 2048 + lane * 8;
        bf16x8 qf0 = *reinterpret_cast<const bf16x8*>(qp);
        bf16x8 qf1 = *reinterpret_cast<const bf16x8*>(qp + 512);
        bf16x8 qf2 = *reinterpret_cast<const bf16x8*>(qp + 1024);
        bf16x8 qf3 = *reinterpret_cast<const bf16x8*>(qp + 1536);

        // hoisted first-tile K/V load: t0 clamped to >=0 (wasted if t0<t_lo, safe)
        const u16* kbase = Kf + tbh * 2048 + lane * 8;
        const u16* vbase = Vf + tbh * 2048 + lane * 8;
        const int t0 = qt - wave;
        const int ta = (t0 >= 0) ? t0 : 0;
        bf16x8 ak0, ak1, ak2, ak3, av0, av1, av2, av3;
        bf16x8 bk0, bk1, bk2, bk3, bv0, bv1, bv2, bv3;
        bf16x8 ck0, ck1, ck2, ck3, cv0, cv1, cv2, cv3;
        LOADT(a, ta)

        // kb from precomputed norms: two scalar chains, no shfl reduce
        const float* kp8 = knp + bh * 8;
        const float knv = fmaxf(fmaxf(fmaxf(kp8[0], kp8[1]), fmaxf(kp8[2], kp8[3])),
                                fmaxf(fmaxf(kp8[4], kp8[5]), fmaxf(kp8[6], kp8[7])));
        const float kb = qn[tbh + qt] * knv * IN2;

        // static window: tail/L < 2^-36 beyond W = (47 + 2kb)/slope2 keys
        const float Wf = (47.f + 2.f * kb) / slope2;
        const int lo_k = qw - 31 - (int)Wf;
        const int t_lo = lo_k <= 0 ? 0 : ((lo_k + 31) >> 5);

        // per-lane softmax addend: cl[r] = slope2*(key_off - la) - kb
        float cl[16];
        #pragma unroll
        for (int r = 0; r < 16; ++r)
            cl[r] = slope2 * (float)((r & 3) + 8 * (r >> 2) + 4 * hi - la) - kb;

        f32x16 o0 = {}, o1 = {};
        float l_i = 0.f;

        if (t0 >= t_lo) {
            const int nit2 = ((t0 - t_lo) >> 2) + 1;
            const int tlast = t0 - 4 * (nit2 - 1);
            const int t1 = (nit2 > 1) ? t0 - 4 : t0;
            LOADT(b, t1)
            {   // iteration 0 (diagonal only for wave 0); loads T(2) into c
                const int t2c = (nit2 > 2) ? t0 - 8 : tlast;
                if (wave == 0) { STEP(a, c, t0, t2c, 1) }
                else           { STEP(a, c, t0, t2c, 0) }
            }
            int i = 1;
            while (i < nit2) {
                {
                    const int tc = t0 - 4 * i;
                    const int tn = (i + 2 < nit2) ? tc - 8 : tlast;
                    STEP(b, a, tc, tn, 0)
                }
                ++i;
                if (i >= nit2) break;
                {
                    const int tc = t0 - 4 * i;
                    const int tn = (i + 2 < nit2) ? tc - 8 : tlast;
                    STEP(c, b, tc, tn, 0)
                }
                ++i;
                if (i >= nit2) break;
                {
                    const int tc = t0 - 4 * i;
                    const int tn = (i + 2 < nit2) ? tc - 8 : tlast;
                    STEP(a, c, tc, tn, 0)
                }
                ++i;
            }
        }

        // ---- write partials (shared static M -> plain sums in combine) ----
        l_i += __shfl_xor(l_i, 32);
        if (hi == 0) ml[wave][la] = l_i;
        #pragma unroll
        for (int r = 0; r < 16; ++r) {
            int d = (r & 3) + 8 * (r >> 2) + 4 * hi;
            o_l[wave][d][la]      = o0[r];
            o_l[wave][d + 32][la] = o1[r];
        }
        __syncthreads();

        // ---- combine: thread = (q, 8-wide d slab); plain sums ----
        const int qq = threadIdx.x >> 3;
        const int d0 = (threadIdx.x & 7) * 8;
        float L = ml[0][qq] + ml[1][qq] + ml[2][qq] + ml[3][qq];
        float inv = 1.0f / L;
        unsigned int packed[4];
        #pragma unroll
        for (int e2 = 0; e2 < 4; ++e2) {
            float Oa = o_l[0][d0 + 2 * e2][qq] + o_l[1][d0 + 2 * e2][qq]
                     + o_l[2][d0 + 2 * e2][qq] + o_l[3][d0 + 2 * e2][qq];
            float Ob = o_l[0][d0 + 2 * e2 + 1][qq] + o_l[1][d0 + 2 * e2 + 1][qq]
                     + o_l[2][d0 + 2 * e2 + 1][qq] + o_l[3][d0 + 2 * e2 + 1][qq];
            packed[e2] = (unsigned)f2bf(Oa * inv) | ((unsigned)f2bf(Ob * inv) << 16);
        }
        const int bb = bh >> 4, hh = bh & 15;
        u32x4 pv; pv[0] = packed[0]; pv[1] = packed[1]; pv[2] = packed[2]; pv[3] = packed[3];
        *reinterpret_cast<u32x4*>(
            &ctx[((size_t)(bb * SEQ + qw + qq)) * HIDDEN + hh * HEAD_DIM + d0]) = pv;
    }
}

extern "C" void kernel_launch(void* const* d_in, const int* in_sizes, int n_in,
                              void* d_out, int out_size, void* d_ws, size_t ws_size,
                              hipStream_t stream) {
    const float* x        = (const float*)d_in[0];
    const float* residual = (const float*)d_in[1];
    const float* alibi    = (const float*)d_in[2];
    const float* W_qkv    = (const float*)d_in[4];
    const float* b_qkv    = (const float*)d_in[5];
    const float* W_dense  = (const float*)d_in[6];
    const float* b_dense  = (const float*)d_in[7];
    float* out = (float*)d_out;

    char* ws = (char*)d_ws;
    u16* xb  = (u16*)(ws);                 //  8 MB  x bf16 fragment-major
    u16* wqb = (u16*)(ws + 8388608);       //  6 MB  W_qkv bf16 fragment-major
    u16* wdb = (u16*)(ws + 14680064);      //  2 MB  W_dense bf16 row-major
    u16* q   = (u16*)(ws + 16777216);      //  8 MB  fragment-major Q tiles
    u16* k   = (u16*)(ws + 25165824);      //  8 MB  fragment-major K tiles
    u16* vT  = (u16*)(ws + 33554432);      //  8 MB  fragment-major V tiles
    u16* ctx = (u16*)(ws + 41943040);      //  8 MB  [B*S][1024]
    float* knp = (float*)(ws + 50331648);  //  1 KB  per-(bh,slice) max ||k||
    float* qn  = (float*)(ws + 50331648 + 1024);   // 8 KB per-(bh,qt) max ||q||
    unsigned int* ctr = (unsigned int*)(ws + 50331648 + 16384);  // 8 group counters

    cvt_all<<<4096, 256, 0, stream>>>(x, W_qkv, W_dense, xb, wqb, wdb);
    gemm_qkv<<<768, 256, 0, stream>>>(xb, wqb, b_qkv, q, k, vT);
    norms<<<256, 256, 0, stream>>>(k, q, knp, qn, ctr);
    attn<<<1024, 256, 0, stream>>>(q, k, vT, alibi, knp, qn, ctx, ctr);
    gemm_dense<<<512, 256, 0, stream>>>(ctx, wdb, b_dense, residual, out);
}

// Round 27
// 120.701 us; speedup vs baseline: 1.0537x; 1.0098x over previous
//
#include <hip/hip_runtime.h>
#include <hip/hip_bf16.h>

#define NUM_HEADS 16
#define HEAD_DIM  64
#define HIDDEN    1024
#define BATCH     2
#define SEQ       2048
#define K_DIM     1024
#define INV_NORM  0.125f
#define LOG2E     1.4426950408889634f
#define IN2       (INV_NORM * LOG2E)

typedef __attribute__((ext_vector_type(4)))  float f32x4;
typedef __attribute__((ext_vector_type(16))) float f32x16;
typedef __attribute__((ext_vector_type(8)))  short bf16x8;
typedef __attribute__((ext_vector_type(4)))  unsigned int u32x4;
typedef __attribute__((ext_vector_type(2)))  unsigned int u32x2;
typedef unsigned short u16;

__device__ inline u16 f2bf(float f) {
    __hip_bfloat16 h = __float2bfloat16(f);
    return __builtin_bit_cast(u16, h);
}
__device__ inline float bf2f(u16 u) {
    unsigned int v = ((unsigned int)u) << 16;
    return __builtin_bit_cast(float, v);
}

__device__ inline f32x16 mfma32(bf16x8 a, bf16x8 b, f32x16 c) {
    return __builtin_amdgcn_mfma_f32_32x32x16_bf16(a, b, c, 0, 0, 0);
}

// async global->LDS, 16B per lane (used by gemm_dense only)
__device__ inline void gl_lds16(const u16* g, u16* s) {
    __builtin_amdgcn_global_load_lds(
        (const __attribute__((address_space(1))) unsigned int*)g,
        (__attribute__((address_space(3))) unsigned int*)s, 16, 0, 0);
}

// ---------------- cvt + pack: x,W_qkv -> fragment-major bf16; W_dense -> row-major ----------------
__device__ inline void pack8(const float* src, u16* dst) {
    const float4 v0 = *reinterpret_cast<const float4*>(src);
    const float4 v1 = *reinterpret_cast<const float4*>(src + 4);
    ushort4 o0, o1;
    o0.x = f2bf(v0.x); o0.y = f2bf(v0.y); o0.z = f2bf(v0.z); o0.w = f2bf(v0.w);
    o1.x = f2bf(v1.x); o1.y = f2bf(v1.y); o1.z = f2bf(v1.z); o1.w = f2bf(v1.w);
    *reinterpret_cast<ushort4*>(dst)     = o0;
    *reinterpret_cast<ushort4*>(dst + 4) = o1;
}
__global__ __launch_bounds__(256) void cvt_all(
        const float* __restrict__ x, const float* __restrict__ wq,
        const float* __restrict__ wd,
        u16* __restrict__ xb, u16* __restrict__ wqb, u16* __restrict__ wdb) {
    int t = blockIdx.x * 256 + threadIdx.x;   // 1048576 threads, 8 elem each
    if (t < 524288) {            // x: 4096 rows -> 128 m-tiles
        int mt = t >> 12, rem = t & 4095;
        int kblk = rem >> 6, hf = (rem >> 5) & 1, ra = rem & 31;
        pack8(x + ((size_t)(mt * 32 + ra)) * K_DIM + kblk * 16 + hf * 8,
              xb + (size_t)t * 8);
    } else if (t < 917504) {     // W_qkv: 3072 rows -> 96 tiles
        int t2 = t - 524288;
        int nt = t2 >> 12, rem = t2 & 4095;
        int kblk = rem >> 6, hf = (rem >> 5) & 1, ra = rem & 31;
        pack8(wq + ((size_t)(nt * 32 + ra)) * K_DIM + kblk * 16 + hf * 8,
              wqb + (size_t)t2 * 8);
    } else {                     // W_dense: plain row-major
        int i = (t - 917504) * 8;
        pack8(wd + i, wdb + i);
    }
}

// ---------------- QKV GEMM: LDS-free, fragment-major direct loads ----------------
#define QLOAD(P, kb) {                                                        \
    P##x0 = *reinterpret_cast<const bf16x8*>(pa0 + (size_t)(kb) * 512);       \
    P##x1 = *reinterpret_cast<const bf16x8*>(pa1 + (size_t)(kb) * 512);       \
    P##y0 = *reinterpret_cast<const bf16x8*>(pb0 + (size_t)(kb) * 512);       \
    P##y1 = *reinterpret_cast<const bf16x8*>(pb1 + (size_t)(kb) * 512);       \
    P##x2 = *reinterpret_cast<const bf16x8*>(pa0 + (size_t)(kb + 1) * 512);   \
    P##x3 = *reinterpret_cast<const bf16x8*>(pa1 + (size_t)(kb + 1) * 512);   \
    P##y2 = *reinterpret_cast<const bf16x8*>(pb0 + (size_t)(kb + 1) * 512);   \
    P##y3 = *reinterpret_cast<const bf16x8*>(pb1 + (size_t)(kb + 1) * 512);   \
}
#define QSTEP(P) {                                                            \
    acc[0][0] = mfma32(P##x0, P##y0, acc[0][0]);                              \
    acc[0][1] = mfma32(P##x0, P##y1, acc[0][1]);                              \
    acc[1][0] = mfma32(P##x1, P##y0, acc[1][0]);                              \
    acc[1][1] = mfma32(P##x1, P##y1, acc[1][1]);                              \
    acc[0][0] = mfma32(P##x2, P##y2, acc[0][0]);                              \
    acc[0][1] = mfma32(P##x2, P##y3, acc[0][1]);                              \
    acc[1][0] = mfma32(P##x3, P##y2, acc[1][0]);                              \
    acc[1][1] = mfma32(P##x3, P##y3, acc[1][1]);                              \
}
__global__ __launch_bounds__(256) void gemm_qkv(
        const u16* __restrict__ Af, const u16* __restrict__ Bf,
        const float* __restrict__ bias,
        u16* __restrict__ qo, u16* __restrict__ ko2, u16* __restrict__ vTo) {
    int lin = blockIdx.x;
    int g = lin & 7, i2 = lin >> 3;           // i2: 0..95
    const int mblk = ((g & 3) * 8 + (i2 & 7)) * 128;
    const int nblk = ((g >> 2) * 12 + (i2 >> 3)) * 128;
    const int tid = threadIdx.x;
    const int w = tid >> 6, lane = tid & 63;
    const int la = lane & 31, hi = lane >> 5;
    const int wr = w >> 1, wc = w & 1;
    const int mt0 = (mblk >> 5) + wr * 2;
    const int nt0 = (nblk >> 5) + wc * 2;
    const u16* pa0 = Af + (size_t)mt0 * 64 * 512 + lane * 8;
    const u16* pa1 = pa0 + 64 * 512;
    const u16* pb0 = Bf + (size_t)nt0 * 64 * 512 + lane * 8;
    const u16* pb1 = pb0 + 64 * 512;
    f32x16 acc[2][2] = {};
    bf16x8 ax0, ax1, ax2, ax3, ay0, ay1, ay2, ay3;
    bf16x8 bx0, bx1, bx2, bx3, by0, by1, by2, by3;
    QLOAD(a, 0)
    #pragma unroll 4
    for (int kb = 0; kb < 64; kb += 4) {
        const int n1 = (kb + 2 < 62) ? kb + 2 : 62;
        QLOAD(b, n1)
        QSTEP(a)
        const int n2 = (kb + 4 < 62) ? kb + 4 : 62;
        QLOAD(a, n2)
        QSTEP(b)
    }
    #pragma unroll
    for (int mi = 0; mi < 2; ++mi)
    #pragma unroll
    for (int ni = 0; ni < 2; ++ni) {
        int c = nblk + wc * 64 + ni * 32 + la;   // fused col: h*192 + which*64 + d
        int h = c / 192, rem = c - h * 192;
        int which = rem >> 6, d = rem & 63;
        float bv = bias[c];
        #pragma unroll
        for (int r = 0; r < 16; ++r) {
            int m = mblk + wr * 64 + mi * 32 + (r & 3) + 8 * (r >> 2) + 4 * hi;
            int bb = m >> 11, s = m & (SEQ - 1);
            int bh = bb * NUM_HEADS + h;
            int t = s >> 5;
            size_t tb = ((size_t)(bh * 64 + t)) * 2048;
            u16 o = f2bf(acc[mi][ni][r] + bv);
            if (which == 2) {
                int dblk = d >> 5, ra = d & 31;
                int k = s & 31, ks = k >> 4, hf = (k >> 3) & 1, e = k & 7;
                vTo[tb + (dblk * 2 + ks) * 512 + hf * 256 + ra * 8 + e] = o;
            } else {
                int kk = d >> 4, hf = (d >> 3) & 1, e = d & 7, ra = s & 31;
                size_t off = tb + kk * 512 + hf * 256 + ra * 8 + e;
                if (which == 0) qo[off] = o;
                else            ko2[off] = o;
            }
        }
    }
}

// ---------------- Dense GEMM + bias + residual: 64x128 tile, 512 blocks (2/CU) ----------------
__global__ __launch_bounds__(256) void gemm_dense(
        const u16* __restrict__ A, const u16* __restrict__ W,
        const float* __restrict__ bias, const float* __restrict__ residual,
        float* __restrict__ out) {
    __shared__ u16 As[64 * 64];
    __shared__ u16 Bs[128 * 64];
    int lin = blockIdx.x;
    int g = lin & 7, i2 = lin >> 3;           // i2: 0..63
    const int mblk = (g * 8 + (i2 & 7)) * 64;
    const int nblk = (i2 >> 3) * 128;
    const int tid = threadIdx.x;
    const int w = tid >> 6, l = tid & 63;
    const int la = l & 31, hi = l >> 5;
    const int wr = w & 1, wc = w >> 1;
    const int kperm = (((l & 7) ^ (l >> 3)) << 3);
    const u16* gA = A + (size_t)(mblk + w * 16 + (l >> 3)) * K_DIM + kperm;
    const u16* gB = W + (size_t)(nblk + w * 32 + (l >> 3)) * K_DIM + kperm;
    const int sca = (la & 7) << 3;
    f32x16 acc2[2] = {};
    for (int kt = 0; kt < 16; ++kt) {
        const int ko = kt * 64;
        gl_lds16(gA + ko,              &As[(w * 16) * 64]);
        gl_lds16(gA + ko + 8 * K_DIM,  &As[(w * 16 + 8) * 64]);
        #pragma unroll
        for (int i = 0; i < 4; ++i)
            gl_lds16(gB + i * 8 * K_DIM + ko, &Bs[(w * 32 + i * 8) * 64]);
        asm volatile("s_waitcnt vmcnt(0)" ::: "memory");
        __syncthreads();
        const u16* pA = &As[(wr * 32 + la) * 64];
        const u16* pB = &Bs[(wc * 64 + la) * 64];
        #pragma unroll
        for (int kk = 0; kk < 4; ++kk) {
            const int co = (kk * 16 + hi * 8) ^ sca;
            bf16x8 a0 = *reinterpret_cast<const bf16x8*>(pA + co);
            bf16x8 b0 = *reinterpret_cast<const bf16x8*>(pB + co);
            bf16x8 b1 = *reinterpret_cast<const bf16x8*>(pB + 32 * 64 + co);
            acc2[0] = mfma32(a0, b0, acc2[0]);
            acc2[1] = mfma32(a0, b1, acc2[1]);
        }
        __syncthreads();
    }
    #pragma unroll
    for (int ni = 0; ni < 2; ++ni) {
        int c = nblk + wc * 64 + ni * 32 + la;
        float bv = bias[c];
        #pragma unroll
        for (int r = 0; r < 16; ++r) {
            int m = mblk + wr * 32 + (r & 3) + 8 * (r >> 2) + 4 * hi;
            out[(size_t)m * HIDDEN + c] = acc2[ni][r] + bv + residual[(size_t)m * HIDDEN + c];
        }
    }
}

// ---------------- norms: per-(bh,slice) max ||k|| partials + per-(bh,qt) max ||q|| ----------------
__global__ __launch_bounds__(256) void norms(
        const u16* __restrict__ Kf, const u16* __restrict__ Qf,
        float* __restrict__ knp, float* __restrict__ qn,
        unsigned int* __restrict__ ctr) {
    if (blockIdx.x == 0 && threadIdx.x < 8) ctr[threadIdx.x] = 0;  // stream-ordered
    __shared__ float red[256];
    const int bh = blockIdx.x >> 3;
    const int s  = (blockIdx.x & 7) * 256 + threadIdx.x;    // one row per thread
    const size_t tb = ((size_t)(bh * 64 + (s >> 5))) * 2048 + (s & 31) * 8;
    float ssk = 0.f, ssq = 0.f;
    #pragma unroll
    for (int kk = 0; kk < 4; ++kk)
    #pragma unroll
    for (int hf = 0; hf < 2; ++hf) {
        bf16x8 v = *reinterpret_cast<const bf16x8*>(Kf + tb + kk * 512 + hf * 256);
        bf16x8 u = *reinterpret_cast<const bf16x8*>(Qf + tb + kk * 512 + hf * 256);
        #pragma unroll
        for (int e = 0; e < 8; ++e) {
            float fk = bf2f((u16)v[e]);
            float fq = bf2f((u16)u[e]);
            ssk = fmaf(fk, fk, ssk);
            ssq = fmaf(fq, fq, ssq);
        }
    }
    float mq = ssq;
    #pragma unroll
    for (int off = 1; off <= 16; off <<= 1) mq = fmaxf(mq, __shfl_xor(mq, off));
    if ((threadIdx.x & 31) == 0)
        qn[(size_t)bh * 64 + (s >> 5)] = sqrtf(mq);
    red[threadIdx.x] = ssk;
    __syncthreads();
    for (int off = 128; off; off >>= 1) {
        if (threadIdx.x < (unsigned)off)
            red[threadIdx.x] = fmaxf(red[threadIdx.x], red[threadIdx.x + off]);
        __syncthreads();
    }
    if (threadIdx.x == 0) knp[blockIdx.x] = sqrtf(red[0]);
}

// ---------------- Flash attention: dual-q-tile items (2 chains/wave) ----------------
// Item = (head, {qt_hi, qt_hi-1}). Per K/V tile: QK+softmax+PV for BOTH q-tiles ->
// 2 independent chains fill each other's stalls; K/V traffic per FLOP halved;
// prologue/atomic amortized 2x. Coverage: wave w steps t = qt_hi-w, -4, ...;
// tiles <= qt_lo seen once each (both sides); qt_hi (wave0) is hi-only.
#define LOADT(P, tt) {                                                        \
    const u16* kp_ = kbase + (size_t)(tt) * 2048;                             \
    P##k0 = *reinterpret_cast<const bf16x8*>(kp_);                            \
    P##k1 = *reinterpret_cast<const bf16x8*>(kp_ + 512);                      \
    P##k2 = *reinterpret_cast<const bf16x8*>(kp_ + 1024);                     \
    P##k3 = *reinterpret_cast<const bf16x8*>(kp_ + 1536);                     \
    const u16* vp_ = vbase + (size_t)(tt) * 2048;                             \
    P##v0 = *reinterpret_cast<const bf16x8*>(vp_);                            \
    P##v1 = *reinterpret_cast<const bf16x8*>(vp_ + 512);                      \
    P##v2 = *reinterpret_cast<const bf16x8*>(vp_ + 1024);                     \
    P##v3 = *reinterpret_cast<const bf16x8*>(vp_ + 1536);                     \
}

// softmax + PV for one side given score regs SA/SB, per-side base, accumulators
#define SMPV(SA, SB, BASEX, DIAGX, LI, OA, OB, P) {                           \
    float p_[16];                                                             \
    _Pragma("unroll")                                                         \
    for (int r = 0; r < 16; ++r) {                                            \
        const float cst_ = (float)((r & 3) + 8 * (r >> 2));                   \
        p_[r] = __builtin_amdgcn_exp2f(                                       \
            fmaf(SA[r] + SB[r], IN2, fmaf(cst_, slope2, BASEX)));             \
    }                                                                         \
    if (DIAGX) {                                                              \
        _Pragma("unroll")                                                     \
        for (int r = 0; r < 16; ++r) {                                        \
            int kr_ = (r & 3) + 8 * (r >> 2) + 4 * hi;                        \
            if (kr_ > la) p_[r] = 0.f;                                        \
        }                                                                     \
    }                                                                         \
    LI += ((p_[0] + p_[1]) + (p_[2] + p_[3])) + ((p_[4] + p_[5]) + (p_[6] + p_[7]))   \
        + ((p_[8] + p_[9]) + (p_[10] + p_[11])) + ((p_[12] + p_[13]) + (p_[14] + p_[15])); \
    unsigned pk_[8];                                                          \
    _Pragma("unroll")                                                         \
    for (int m = 0; m < 4; ++m) {                                             \
        unsigned b0_ = __builtin_bit_cast(unsigned, p_[4 * m])     + 0x8000u; \
        unsigned b1_ = __builtin_bit_cast(unsigned, p_[4 * m + 1]) + 0x8000u; \
        unsigned b2_ = __builtin_bit_cast(unsigned, p_[4 * m + 2]) + 0x8000u; \
        unsigned b3_ = __builtin_bit_cast(unsigned, p_[4 * m + 3]) + 0x8000u; \
        pk_[2 * m]     = __builtin_amdgcn_perm(b1_, b0_, 0x07060302u);        \
        pk_[2 * m + 1] = __builtin_amdgcn_perm(b3_, b2_, 0x07060302u);        \
    }                                                                         \
    u32x2 r0_ = __builtin_amdgcn_permlane32_swap(pk_[0], pk_[2], false, false); \
    u32x2 r1_ = __builtin_amdgcn_permlane32_swap(pk_[1], pk_[3], false, false); \
    u32x2 r2_ = __builtin_amdgcn_permlane32_swap(pk_[4], pk_[6], false, false); \
    u32x2 r3_ = __builtin_amdgcn_permlane32_swap(pk_[5], pk_[7], false, false); \
    u32x4 pb0_, pb1_;                                                         \
    pb0_[0] = r0_[0]; pb0_[1] = r1_[0]; pb0_[2] = r0_[1]; pb0_[3] = r1_[1];   \
    pb1_[0] = r2_[0]; pb1_[1] = r3_[0]; pb1_[2] = r2_[1]; pb1_[3] = r3_[1];   \
    bf16x8 pf0_ = __builtin_bit_cast(bf16x8, pb0_);                           \
    bf16x8 pf1_ = __builtin_bit_cast(bf16x8, pb1_);                           \
    OA = mfma32(P##v0, pf0_, OA);                                             \
    OA = mfma32(P##v1, pf1_, OA);                                             \
    OB = mfma32(P##v2, pf0_, OB);                                             \
    OB = mfma32(P##v3, pf1_, OB);                                             \
}

#define STEP2(P, N, tcur, tnxt, DIAGH, DOLO, DIAGL) {                         \
    const int k0_ = (tcur) * 32;                                              \
    f32x16 sha_ = {}, shb_ = {};                                              \
    sha_ = mfma32(P##k0, qfh0, sha_);                                         \
    shb_ = mfma32(P##k1, qfh1, shb_);                                         \
    sha_ = mfma32(P##k2, qfh2, sha_);                                         \
    shb_ = mfma32(P##k3, qfh3, shb_);                                         \
    f32x16 sla_ = {}, slb_ = {};                                              \
    if (DOLO) {                                                               \
        sla_ = mfma32(P##k0, qfl0, sla_);                                     \
        slb_ = mfma32(P##k1, qfl1, slb_);                                     \
        sla_ = mfma32(P##k2, qfl2, sla_);                                     \
        slb_ = mfma32(P##k3, qfl3, slb_);                                     \
    }                                                                         \
    LOADT(N, tnxt)                                                            \
    {                                                                         \
        const float baseh_ = fmaf(slope2, (float)(k0_ - qw_hi), C0 - kb_h);   \
        SMPV(sha_, shb_, baseh_, DIAGH, l_h, o0h, o1h, P)                     \
    }                                                                         \
    if (DOLO) {                                                               \
        const float basel_ = fmaf(slope2, (float)(k0_ - qw_lo), C0 - kb_l);   \
        SMPV(sla_, slb_, basel_, DIAGL, l_l, o0l, o1l, P)                     \
    }                                                                         \
}

__global__ __launch_bounds__(256) void attn(
        const u16* __restrict__ Qf, const u16* __restrict__ Kf,
        const u16* __restrict__ Vf, const float* __restrict__ alibi,
        const float* __restrict__ knp, const float* __restrict__ qn,
        u16* __restrict__ ctx, unsigned int* __restrict__ ctr) {
    __shared__ float o_l[4][64][33];
    __shared__ float ml[4][32];
    __shared__ unsigned int s_idx;
    const int grp  = blockIdx.x & 7;
    const int lst  = grp >> 1;
    const int bat  = grp & 1;
    // packed bh-head lists (byte j = head of slot j); 32 qt-pairs per slot
    const unsigned long long LH = (lst == 0) ? 0x0000000007080Full
                               : (lst == 1) ? 0x000000000006090Eull
                               : (lst == 2) ? 0x0000000003050A0Dull
                                            : 0x00000102040B0Cull;
    const unsigned nit = (lst == 0) ? 96u : (lst == 3) ? 160u : 128u;
    const int wave = __builtin_amdgcn_readfirstlane(threadIdx.x >> 6);  // SGPR
    const int lane = threadIdx.x & 63;
    const int la = lane & 31, hi = lane >> 5;

    for (;;) {
        if (threadIdx.x == 0) s_idx = atomicAdd(ctr + grp, 1u);
        __syncthreads();                     // publish s_idx; protect o_l reuse
        const unsigned int idx = s_idx;
        if (idx >= nit) return;
        const int h  = (int)((LH >> (8 * (idx >> 5))) & 0xFF);
        const int pr = (int)(idx & 31u);
        const int qt_hi = 63 - 2 * pr;       // pairs: (63,62),(61,60),...,(1,0)
        const int qt_lo = qt_hi - 1;
        const int bh = bat * 16 + h;
        const int qw_hi = qt_hi * 32;
        const int qw_lo = qw_hi - 32;
        const size_t tbh = (size_t)bh * 64;
        const float slope2 = alibi[(size_t)bh * SEQ + 1] * LOG2E;

        // Q fragments for both q-tiles
        const u16* qph = Qf + (tbh + qt_hi) * 2048 + lane * 8;
        bf16x8 qfh0 = *reinterpret_cast<const bf16x8*>(qph);
        bf16x8 qfh1 = *reinterpret_cast<const bf16x8*>(qph + 512);
        bf16x8 qfh2 = *reinterpret_cast<const bf16x8*>(qph + 1024);
        bf16x8 qfh3 = *reinterpret_cast<const bf16x8*>(qph + 1536);
        const u16* qpl = qph - 2048;
        bf16x8 qfl0 = *reinterpret_cast<const bf16x8*>(qpl);
        bf16x8 qfl1 = *reinterpret_cast<const bf16x8*>(qpl + 512);
        bf16x8 qfl2 = *reinterpret_cast<const bf16x8*>(qpl + 1024);
        bf16x8 qfl3 = *reinterpret_cast<const bf16x8*>(qpl + 1536);

        // hoisted first-tile K/V load
        const u16* kbase = Kf + tbh * 2048 + lane * 8;
        const u16* vbase = Vf + tbh * 2048 + lane * 8;
        const int t0 = qt_hi - wave;
        const int ta = (t0 >= 0) ? t0 : 0;
        bf16x8 ak0, ak1, ak2, ak3, av0, av1, av2, av3;
        bf16x8 bk0, bk1, bk2, bk3, bv0, bv1, bv2, bv3;
        LOADT(a, ta)

        // kb per side from precomputed norms
        const float* kp8 = knp + bh * 8;
        const float knv = fmaxf(fmaxf(fmaxf(kp8[0], kp8[1]), fmaxf(kp8[2], kp8[3])),
                                fmaxf(fmaxf(kp8[4], kp8[5]), fmaxf(kp8[6], kp8[7])));
        const float kb_h = qn[tbh + qt_hi] * knv * IN2;
        const float kb_l = qn[tbh + qt_lo] * knv * IN2;
        const float C0 = slope2 * (float)(4 * hi - la);

        // static windows; loop to t_min = min (extra tiles only add accurate terms)
        const float Wh = (47.f + 2.f * kb_h) / slope2;
        const float Wl = (47.f + 2.f * kb_l) / slope2;
        const int lo_kh = qw_hi - 31 - (int)Wh;
        const int lo_kl = qw_lo - 31 - (int)Wl;
        const int t_lh = lo_kh <= 0 ? 0 : ((lo_kh + 31) >> 5);
        const int t_ll = lo_kl <= 0 ? 0 : ((lo_kl + 31) >> 5);
        const int t_min = (t_lh < t_ll) ? t_lh : t_ll;

        f32x16 o0h = {}, o1h = {}, o0l = {}, o1l = {};
        float l_h = 0.f, l_l = 0.f;

        if (t0 >= t_min) {
            const int nit2 = ((t0 - t_min) >> 2) + 1;
            const int t1 = (nit2 > 1) ? t0 - 4 : t0;
            // peeled first iteration: flags by wave
            if (wave == 0)      { STEP2(a, b, t0, t1, 1, 0, 0) }   // hi diag, lo absent
            else if (wave == 1) { STEP2(a, b, t0, t1, 0, 1, 1) }   // lo diag
            else                { STEP2(a, b, t0, t1, 0, 1, 0) }
            int i = 1;
            while (i < nit2) {
                {
                    const int tc = t0 - 4 * i;
                    const int tn = (i + 1 < nit2) ? tc - 4 : tc;
                    STEP2(b, a, tc, tn, 0, 1, 0)
                }
                ++i;
                if (i >= nit2) break;
                {
                    const int tc = t0 - 4 * i;
                    const int tn = (i + 1 < nit2) ? tc - 4 : tc;
                    STEP2(a, b, tc, tn, 0, 1, 0)
                }
                ++i;
            }
        }

        const int qq = threadIdx.x >> 3;
        const int d0 = (threadIdx.x & 7) * 8;
        const int bb = bh >> 4, hh = bh & 15;

        // ---- combine HI ----
        l_h += __shfl_xor(l_h, 32);
        if (hi == 0) ml[wave][la] = l_h;
        #pragma unroll
        for (int r = 0; r < 16; ++r) {
            int d = (r & 3) + 8 * (r >> 2) + 4 * hi;
            o_l[wave][d][la]      = o0h[r];
            o_l[wave][d + 32][la] = o1h[r];
        }
        __syncthreads();
        {
            float L = ml[0][qq] + ml[1][qq] + ml[2][qq] + ml[3][qq];
            float inv = 1.0f / L;
            unsigned int packed[4];
            #pragma unroll
            for (int e2 = 0; e2 < 4; ++e2) {
                float Oa = o_l[0][d0 + 2 * e2][qq] + o_l[1][d0 + 2 * e2][qq]
                         + o_l[2][d0 + 2 * e2][qq] + o_l[3][d0 + 2 * e2][qq];
                float Ob = o_l[0][d0 + 2 * e2 + 1][qq] + o_l[1][d0 + 2 * e2 + 1][qq]
                         + o_l[2][d0 + 2 * e2 + 1][qq] + o_l[3][d0 + 2 * e2 + 1][qq];
                packed[e2] = (unsigned)f2bf(Oa * inv) | ((unsigned)f2bf(Ob * inv) << 16);
            }
            u32x4 pv; pv[0] = packed[0]; pv[1] = packed[1]; pv[2] = packed[2]; pv[3] = packed[3];
            *reinterpret_cast<u32x4*>(
                &ctx[((size_t)(bb * SEQ + qw_hi + qq)) * HIDDEN + hh * HEAD_DIM + d0]) = pv;
        }
        __syncthreads();   // all hi reads done before lo overwrites

        // ---- combine LO ----
        l_l += __shfl_xor(l_l, 32);
        if (hi == 0) ml[wave][la] = l_l;
        #pragma unroll
        for (int r = 0; r < 16; ++r) {
            int d = (r & 3) + 8 * (r >> 2) + 4 * hi;
            o_l[wave][d][la]      = o0l[r];
            o_l[wave][d + 32][la] = o1l[r];
        }
        __syncthreads();
        {
            float L = ml[0][qq] + ml[1][qq] + ml[2][qq] + ml[3][qq];
            float inv = 1.0f / L;
            unsigned int packed[4];
            #pragma unroll
            for (int e2 = 0; e2 < 4; ++e2) {
                float Oa = o_l[0][d0 + 2 * e2][qq] + o_l[1][d0 + 2 * e2][qq]
                         + o_l[2][d0 + 2 * e2][qq] + o_l[3][d0 + 2 * e2][qq];
                float Ob = o_l[0][d0 + 2 * e2 + 1][qq] + o_l[1][d0 + 2 * e2 + 1][qq]
                         + o_l[2][d0 + 2 * e2 + 1][qq] + o_l[3][d0 + 2 * e2 + 1][qq];
                packed[e2] = (unsigned)f2bf(Oa * inv) | ((unsigned)f2bf(Ob * inv) << 16);
            }
            u32x4 pv; pv[0] = packed[0]; pv[1] = packed[1]; pv[2] = packed[2]; pv[3] = packed[3];
            *reinterpret_cast<u32x4*>(
                &ctx[((size_t)(bb * SEQ + qw_lo + qq)) * HIDDEN + hh * HEAD_DIM + d0]) = pv;
        }
    }
}

extern "C" void kernel_launch(void* const* d_in, const int* in_sizes, int n_in,
                              void* d_out, int out_size, void* d_ws, size_t ws_size,
                              hipStream_t stream) {
    const float* x        = (const float*)d_in[0];
    const float* residual = (const float*)d_in[1];
    const float* alibi    = (const float*)d_in[2];
    const float* W_qkv    = (const float*)d_in[4];
    const float* b_qkv    = (const float*)d_in[5];
    const float* W_dense  = (const float*)d_in[6];
    const float* b_dense  = (const float*)d_in[7];
    float* out = (float*)d_out;

    char* ws = (char*)d_ws;
    u16* xb  = (u16*)(ws);                 //  8 MB  x bf16 fragment-major
    u16* wqb = (u16*)(ws + 8388608);       //  6 MB  W_qkv bf16 fragment-major
    u16* wdb = (u16*)(ws + 14680064);      //  2 MB  W_dense bf16 row-major
    u16* q   = (u16*)(ws + 16777216);      //  8 MB  fragment-major Q tiles
    u16* k   = (u16*)(ws + 25165824);      //  8 MB  fragment-major K tiles
    u16* vT  = (u16*)(ws + 33554432);      //  8 MB  fragment-major V tiles
    u16* ctx = (u16*)(ws + 41943040);      //  8 MB  [B*S][1024]
    float* knp = (float*)(ws + 50331648);  //  1 KB  per-(bh,slice) max ||k||
    float* qn  = (float*)(ws + 50331648 + 1024);   // 8 KB per-(bh,qt) max ||q||
    unsigned int* ctr = (unsigned int*)(ws + 50331648 + 16384);  // 8 group counters

    cvt_all<<<4096, 256, 0, stream>>>(x, W_qkv, W_dense, xb, wqb, wdb);
    gemm_qkv<<<768, 256, 0, stream>>>(xb, wqb, b_qkv, q, k, vT);
    norms<<<256, 256, 0, stream>>>(k, q, knp, qn, ctr);
    attn<<<1024, 256, 0, stream>>>(q, k, vT, alibi, knp, qn, ctx, ctr);
    gemm_dense<<<512, 256, 0, stream>>>(ctx, wdb, b_dense, residual, out);
}

// Round 28
// 117.607 us; speedup vs baseline: 1.0814x; 1.0263x over previous
//
#include <hip/hip_runtime.h>
#include <hip/hip_bf16.h>

#define NUM_HEADS 16
#define HEAD_DIM  64
#define HIDDEN    1024
#define BATCH     2
#define SEQ       2048
#define K_DIM     1024
#define INV_NORM  0.125f
#define LOG2E     1.4426950408889634f
#define IN2       (INV_NORM * LOG2E)

typedef __attribute__((ext_vector_type(4)))  float f32x4;
typedef __attribute__((ext_vector_type(16))) float f32x16;
typedef __attribute__((ext_vector_type(8)))  short bf16x8;
typedef __attribute__((ext_vector_type(4)))  unsigned int u32x4;
typedef __attribute__((ext_vector_type(2)))  unsigned int u32x2;
typedef unsigned short u16;

__device__ inline u16 f2bf(float f) {
    __hip_bfloat16 h = __float2bfloat16(f);
    return __builtin_bit_cast(u16, h);
}
__device__ inline float bf2f(u16 u) {
    unsigned int v = ((unsigned int)u) << 16;
    return __builtin_bit_cast(float, v);
}

__device__ inline f32x16 mfma32(bf16x8 a, bf16x8 b, f32x16 c) {
    return __builtin_amdgcn_mfma_f32_32x32x16_bf16(a, b, c, 0, 0, 0);
}

// async global->LDS, 16B per lane (used by gemm_dense only)
__device__ inline void gl_lds16(const u16* g, u16* s) {
    __builtin_amdgcn_global_load_lds(
        (const __attribute__((address_space(1))) unsigned int*)g,
        (__attribute__((address_space(3))) unsigned int*)s, 16, 0, 0);
}

// ---------------- cvt + pack: x,W_qkv -> fragment-major bf16; W_dense -> row-major ----------------
__device__ inline void pack8(const float* src, u16* dst) {
    const float4 v0 = *reinterpret_cast<const float4*>(src);
    const float4 v1 = *reinterpret_cast<const float4*>(src + 4);
    ushort4 o0, o1;
    o0.x = f2bf(v0.x); o0.y = f2bf(v0.y); o0.z = f2bf(v0.z); o0.w = f2bf(v0.w);
    o1.x = f2bf(v1.x); o1.y = f2bf(v1.y); o1.z = f2bf(v1.z); o1.w = f2bf(v1.w);
    *reinterpret_cast<ushort4*>(dst)     = o0;
    *reinterpret_cast<ushort4*>(dst + 4) = o1;
}
__global__ __launch_bounds__(256) void cvt_all(
        const float* __restrict__ x, const float* __restrict__ wq,
        const float* __restrict__ wd,
        u16* __restrict__ xb, u16* __restrict__ wqb, u16* __restrict__ wdb) {
    int t = blockIdx.x * 256 + threadIdx.x;   // 1048576 threads, 8 elem each
    if (t < 524288) {            // x: 4096 rows -> 128 m-tiles
        int mt = t >> 12, rem = t & 4095;
        int kblk = rem >> 6, hf = (rem >> 5) & 1, ra = rem & 31;
        pack8(x + ((size_t)(mt * 32 + ra)) * K_DIM + kblk * 16 + hf * 8,
              xb + (size_t)t * 8);
    } else if (t < 917504) {     // W_qkv: 3072 rows -> 96 tiles
        int t2 = t - 524288;
        int nt = t2 >> 12, rem = t2 & 4095;
        int kblk = rem >> 6, hf = (rem >> 5) & 1, ra = rem & 31;
        pack8(wq + ((size_t)(nt * 32 + ra)) * K_DIM + kblk * 16 + hf * 8,
              wqb + (size_t)t2 * 8);
    } else {                     // W_dense: plain row-major
        int i = (t - 917504) * 8;
        pack8(wd + i, wdb + i);
    }
}

// ---------------- QKV GEMM: LDS-free, fragment-major direct loads ----------------
#define QLOAD(P, kb) {                                                        \
    P##x0 = *reinterpret_cast<const bf16x8*>(pa0 + (size_t)(kb) * 512);       \
    P##x1 = *reinterpret_cast<const bf16x8*>(pa1 + (size_t)(kb) * 512);       \
    P##y0 = *reinterpret_cast<const bf16x8*>(pb0 + (size_t)(kb) * 512);       \
    P##y1 = *reinterpret_cast<const bf16x8*>(pb1 + (size_t)(kb) * 512);       \
    P##x2 = *reinterpret_cast<const bf16x8*>(pa0 + (size_t)(kb + 1) * 512);   \
    P##x3 = *reinterpret_cast<const bf16x8*>(pa1 + (size_t)(kb + 1) * 512);   \
    P##y2 = *reinterpret_cast<const bf16x8*>(pb0 + (size_t)(kb + 1) * 512);   \
    P##y3 = *reinterpret_cast<const bf16x8*>(pb1 + (size_t)(kb + 1) * 512);   \
}
#define QSTEP(P) {                                                            \
    acc[0][0] = mfma32(P##x0, P##y0, acc[0][0]);                              \
    acc[0][1] = mfma32(P##x0, P##y1, acc[0][1]);                              \
    acc[1][0] = mfma32(P##x1, P##y0, acc[1][0]);                              \
    acc[1][1] = mfma32(P##x1, P##y1, acc[1][1]);                              \
    acc[0][0] = mfma32(P##x2, P##y2, acc[0][0]);                              \
    acc[0][1] = mfma32(P##x2, P##y3, acc[0][1]);                              \
    acc[1][0] = mfma32(P##x3, P##y2, acc[1][0]);                              \
    acc[1][1] = mfma32(P##x3, P##y3, acc[1][1]);                              \
}
__global__ __launch_bounds__(256) void gemm_qkv(
        const u16* __restrict__ Af, const u16* __restrict__ Bf,
        const float* __restrict__ bias,
        u16* __restrict__ qo, u16* __restrict__ ko2, u16* __restrict__ vTo) {
    int lin = blockIdx.x;
    int g = lin & 7, i2 = lin >> 3;           // i2: 0..95
    const int mblk = ((g & 3) * 8 + (i2 & 7)) * 128;
    const int nblk = ((g >> 2) * 12 + (i2 >> 3)) * 128;
    const int tid = threadIdx.x;
    const int w = tid >> 6, lane = tid & 63;
    const int la = lane & 31, hi = lane >> 5;
    const int wr = w >> 1, wc = w & 1;
    const int mt0 = (mblk >> 5) + wr * 2;
    const int nt0 = (nblk >> 5) + wc * 2;
    const u16* pa0 = Af + (size_t)mt0 * 64 * 512 + lane * 8;
    const u16* pa1 = pa0 + 64 * 512;
    const u16* pb0 = Bf + (size_t)nt0 * 64 * 512 + lane * 8;
    const u16* pb1 = pb0 + 64 * 512;
    f32x16 acc[2][2] = {};
    bf16x8 ax0, ax1, ax2, ax3, ay0, ay1, ay2, ay3;
    bf16x8 bx0, bx1, bx2, bx3, by0, by1, by2, by3;
    QLOAD(a, 0)
    #pragma unroll 4
    for (int kb = 0; kb < 64; kb += 4) {
        const int n1 = (kb + 2 < 62) ? kb + 2 : 62;
        QLOAD(b, n1)
        QSTEP(a)
        const int n2 = (kb + 4 < 62) ? kb + 4 : 62;
        QLOAD(a, n2)
        QSTEP(b)
    }
    #pragma unroll
    for (int mi = 0; mi < 2; ++mi)
    #pragma unroll
    for (int ni = 0; ni < 2; ++ni) {
        int c = nblk + wc * 64 + ni * 32 + la;   // fused col: h*192 + which*64 + d
        int h = c / 192, rem = c - h * 192;
        int which = rem >> 6, d = rem & 63;
        float bv = bias[c];
        #pragma unroll
        for (int r = 0; r < 16; ++r) {
            int m = mblk + wr * 64 + mi * 32 + (r & 3) + 8 * (r >> 2) + 4 * hi;
            int bb = m >> 11, s = m & (SEQ - 1);
            int bh = bb * NUM_HEADS + h;
            int t = s >> 5;
            size_t tb = ((size_t)(bh * 64 + t)) * 2048;
            u16 o = f2bf(acc[mi][ni][r] + bv);
            if (which == 2) {
                int dblk = d >> 5, ra = d & 31;
                int k = s & 31, ks = k >> 4, hf = (k >> 3) & 1, e = k & 7;
                vTo[tb + (dblk * 2 + ks) * 512 + hf * 256 + ra * 8 + e] = o;
            } else {
                int kk = d >> 4, hf = (d >> 3) & 1, e = d & 7, ra = s & 31;
                size_t off = tb + kk * 512 + hf * 256 + ra * 8 + e;
                if (which == 0) qo[off] = o;
                else            ko2[off] = o;
            }
        }
    }
}

// ---------------- Dense GEMM + bias + residual: 64x128 tile, 512 blocks (2/CU) ----------------
__global__ __launch_bounds__(256) void gemm_dense(
        const u16* __restrict__ A, const u16* __restrict__ W,
        const float* __restrict__ bias, const float* __restrict__ residual,
        float* __restrict__ out) {
    __shared__ u16 As[64 * 64];
    __shared__ u16 Bs[128 * 64];
    int lin = blockIdx.x;
    int g = lin & 7, i2 = lin >> 3;           // i2: 0..63
    const int mblk = (g * 8 + (i2 & 7)) * 64;
    const int nblk = (i2 >> 3) * 128;
    const int tid = threadIdx.x;
    const int w = tid >> 6, l = tid & 63;
    const int la = l & 31, hi = l >> 5;
    const int wr = w & 1, wc = w >> 1;
    const int kperm = (((l & 7) ^ (l >> 3)) << 3);
    const u16* gA = A + (size_t)(mblk + w * 16 + (l >> 3)) * K_DIM + kperm;
    const u16* gB = W + (size_t)(nblk + w * 32 + (l >> 3)) * K_DIM + kperm;
    const int sca = (la & 7) << 3;
    f32x16 acc2[2] = {};
    for (int kt = 0; kt < 16; ++kt) {
        const int ko = kt * 64;
        gl_lds16(gA + ko,              &As[(w * 16) * 64]);
        gl_lds16(gA + ko + 8 * K_DIM,  &As[(w * 16 + 8) * 64]);
        #pragma unroll
        for (int i = 0; i < 4; ++i)
            gl_lds16(gB + i * 8 * K_DIM + ko, &Bs[(w * 32 + i * 8) * 64]);
        asm volatile("s_waitcnt vmcnt(0)" ::: "memory");
        __syncthreads();
        const u16* pA = &As[(wr * 32 + la) * 64];
        const u16* pB = &Bs[(wc * 64 + la) * 64];
        #pragma unroll
        for (int kk = 0; kk < 4; ++kk) {
            const int co = (kk * 16 + hi * 8) ^ sca;
            bf16x8 a0 = *reinterpret_cast<const bf16x8*>(pA + co);
            bf16x8 b0 = *reinterpret_cast<const bf16x8*>(pB + co);
            bf16x8 b1 = *reinterpret_cast<const bf16x8*>(pB + 32 * 64 + co);
            acc2[0] = mfma32(a0, b0, acc2[0]);
            acc2[1] = mfma32(a0, b1, acc2[1]);
        }
        __syncthreads();
    }
    #pragma unroll
    for (int ni = 0; ni < 2; ++ni) {
        int c = nblk + wc * 64 + ni * 32 + la;
        float bv = bias[c];
        #pragma unroll
        for (int r = 0; r < 16; ++r) {
            int m = mblk + wr * 32 + (r & 3) + 8 * (r >> 2) + 4 * hi;
            out[(size_t)m * HIDDEN + c] = acc2[ni][r] + bv + residual[(size_t)m * HIDDEN + c];
        }
    }
}

// ---------------- norms: per-(bh,slice) max ||k|| partials + per-(bh,qt) max ||q|| ----------------
__global__ __launch_bounds__(256) void norms(
        const u16* __restrict__ Kf, const u16* __restrict__ Qf,
        float* __restrict__ knp, float* __restrict__ qn,
        unsigned int* __restrict__ ctr) {
    if (blockIdx.x == 0 && threadIdx.x < 8) ctr[threadIdx.x] = 0;  // stream-ordered
    __shared__ float red[256];
    const int bh = blockIdx.x >> 3;
    const int s  = (blockIdx.x & 7) * 256 + threadIdx.x;    // one row per thread
    const size_t tb = ((size_t)(bh * 64 + (s >> 5))) * 2048 + (s & 31) * 8;
    float ssk = 0.f, ssq = 0.f;
    #pragma unroll
    for (int kk = 0; kk < 4; ++kk)
    #pragma unroll
    for (int hf = 0; hf < 2; ++hf) {
        bf16x8 v = *reinterpret_cast<const bf16x8*>(Kf + tb + kk * 512 + hf * 256);
        bf16x8 u = *reinterpret_cast<const bf16x8*>(Qf + tb + kk * 512 + hf * 256);
        #pragma unroll
        for (int e = 0; e < 8; ++e) {
            float fk = bf2f((u16)v[e]);
            float fq = bf2f((u16)u[e]);
            ssk = fmaf(fk, fk, ssk);
            ssq = fmaf(fq, fq, ssq);
        }
    }
    float mq = ssq;
    #pragma unroll
    for (int off = 1; off <= 16; off <<= 1) mq = fmaxf(mq, __shfl_xor(mq, off));
    if ((threadIdx.x & 31) == 0)
        qn[(size_t)bh * 64 + (s >> 5)] = sqrtf(mq);
    red[threadIdx.x] = ssk;
    __syncthreads();
    for (int off = 128; off; off >>= 1) {
        if (threadIdx.x < (unsigned)off)
            red[threadIdx.x] = fmaxf(red[threadIdx.x], red[threadIdx.x + off]);
        __syncthreads();
    }
    if (threadIdx.x == 0) knp[blockIdx.x] = sqrtf(red[0]);
}

// ---------------- Flash attention: dual-q-tile items (2 chains/wave) ----------------
#define LOADT(P, tt) {                                                        \
    const u16* kp_ = kbase + (size_t)(tt) * 2048;                             \
    P##k0 = *reinterpret_cast<const bf16x8*>(kp_);                            \
    P##k1 = *reinterpret_cast<const bf16x8*>(kp_ + 512);                      \
    P##k2 = *reinterpret_cast<const bf16x8*>(kp_ + 1024);                     \
    P##k3 = *reinterpret_cast<const bf16x8*>(kp_ + 1536);                     \
    const u16* vp_ = vbase + (size_t)(tt) * 2048;                             \
    P##v0 = *reinterpret_cast<const bf16x8*>(vp_);                            \
    P##v1 = *reinterpret_cast<const bf16x8*>(vp_ + 512);                      \
    P##v2 = *reinterpret_cast<const bf16x8*>(vp_ + 1024);                     \
    P##v3 = *reinterpret_cast<const bf16x8*>(vp_ + 1536);                     \
}

// softmax + PV for one side given score regs SA/SB, per-side base, accumulators
#define SMPV(SA, SB, BASEX, DIAGX, LI, OA, OB, P) {                           \
    float p_[16];                                                             \
    _Pragma("unroll")                                                         \
    for (int r = 0; r < 16; ++r) {                                            \
        const float cst_ = (float)((r & 3) + 8 * (r >> 2));                   \
        p_[r] = __builtin_amdgcn_exp2f(                                       \
            fmaf(SA[r] + SB[r], IN2, fmaf(cst_, slope2, BASEX)));             \
    }                                                                         \
    if (DIAGX) {                                                              \
        _Pragma("unroll")                                                     \
        for (int r = 0; r < 16; ++r) {                                        \
            int kr_ = (r & 3) + 8 * (r >> 2) + 4 * hi;                        \
            if (kr_ > la) p_[r] = 0.f;                                        \
        }                                                                     \
    }                                                                         \
    LI += ((p_[0] + p_[1]) + (p_[2] + p_[3])) + ((p_[4] + p_[5]) + (p_[6] + p_[7]))   \
        + ((p_[8] + p_[9]) + (p_[10] + p_[11])) + ((p_[12] + p_[13]) + (p_[14] + p_[15])); \
    unsigned pk_[8];                                                          \
    _Pragma("unroll")                                                         \
    for (int m = 0; m < 4; ++m) {                                             \
        unsigned b0_ = __builtin_bit_cast(unsigned, p_[4 * m])     + 0x8000u; \
        unsigned b1_ = __builtin_bit_cast(unsigned, p_[4 * m + 1]) + 0x8000u; \
        unsigned b2_ = __builtin_bit_cast(unsigned, p_[4 * m + 2]) + 0x8000u; \
        unsigned b3_ = __builtin_bit_cast(unsigned, p_[4 * m + 3]) + 0x8000u; \
        pk_[2 * m]     = __builtin_amdgcn_perm(b1_, b0_, 0x07060302u);        \
        pk_[2 * m + 1] = __builtin_amdgcn_perm(b3_, b2_, 0x07060302u);        \
    }                                                                         \
    u32x2 r0_ = __builtin_amdgcn_permlane32_swap(pk_[0], pk_[2], false, false); \
    u32x2 r1_ = __builtin_amdgcn_permlane32_swap(pk_[1], pk_[3], false, false); \
    u32x2 r2_ = __builtin_amdgcn_permlane32_swap(pk_[4], pk_[6], false, false); \
    u32x2 r3_ = __builtin_amdgcn_permlane32_swap(pk_[5], pk_[7], false, false); \
    u32x4 pb0_, pb1_;                                                         \
    pb0_[0] = r0_[0]; pb0_[1] = r1_[0]; pb0_[2] = r0_[1]; pb0_[3] = r1_[1];   \
    pb1_[0] = r2_[0]; pb1_[1] = r3_[0]; pb1_[2] = r2_[1]; pb1_[3] = r3_[1];   \
    bf16x8 pf0_ = __builtin_bit_cast(bf16x8, pb0_);                           \
    bf16x8 pf1_ = __builtin_bit_cast(bf16x8, pb1_);                           \
    OA = mfma32(P##v0, pf0_, OA);                                             \
    OA = mfma32(P##v1, pf1_, OA);                                             \
    OB = mfma32(P##v2, pf0_, OB);                                             \
    OB = mfma32(P##v3, pf1_, OB);                                             \
}

#define STEP2(P, N, tcur, tnxt, DIAGH, DOLO, DIAGL) {                         \
    const int k0_ = (tcur) * 32;                                              \
    f32x16 sha_ = {}, shb_ = {};                                              \
    sha_ = mfma32(P##k0, qfh0, sha_);                                         \
    shb_ = mfma32(P##k1, qfh1, shb_);                                         \
    sha_ = mfma32(P##k2, qfh2, sha_);                                         \
    shb_ = mfma32(P##k3, qfh3, shb_);                                         \
    f32x16 sla_ = {}, slb_ = {};                                              \
    if (DOLO) {                                                               \
        sla_ = mfma32(P##k0, qfl0, sla_);                                     \
        slb_ = mfma32(P##k1, qfl1, slb_);                                     \
        sla_ = mfma32(P##k2, qfl2, sla_);                                     \
        slb_ = mfma32(P##k3, qfl3, slb_);                                     \
    }                                                                         \
    LOADT(N, tnxt)                                                            \
    {                                                                         \
        const float baseh_ = fmaf(slope2, (float)(k0_ - qw_hi), C0 - kb_h);   \
        SMPV(sha_, shb_, baseh_, DIAGH, l_h, o0h, o1h, P)                     \
    }                                                                         \
    if (DOLO) {                                                               \
        const float basel_ = fmaf(slope2, (float)(k0_ - qw_lo), C0 - kb_l);   \
        SMPV(sla_, slb_, basel_, DIAGL, l_l, o0l, o1l, P)                     \
    }                                                                         \
}

__global__ __launch_bounds__(256) void attn(
        const u16* __restrict__ Qf, const u16* __restrict__ Kf,
        const u16* __restrict__ Vf, const float* __restrict__ alibi,
        const float* __restrict__ knp, const float* __restrict__ qn,
        u16* __restrict__ ctx, unsigned int* __restrict__ ctr) {
    __shared__ float o_l[4][64][33];
    __shared__ float ml[4][32];
    __shared__ unsigned int s_idx;
    const int grp  = blockIdx.x & 7;
    const int lst  = grp >> 1;
    const int bat  = grp & 1;
    // packed bh-head lists (byte j = head of slot j); 32 qt-pairs per slot
    const unsigned long long LH = (lst == 0) ? 0x0000000007080Full
                               : (lst == 1) ? 0x000000000006090Eull
                               : (lst == 2) ? 0x0000000003050A0Dull
                                            : 0x00000102040B0Cull;
    const unsigned nit = (lst == 0) ? 96u : (lst == 3) ? 160u : 128u;
    const int wave = __builtin_amdgcn_readfirstlane(threadIdx.x >> 6);  // SGPR
    const int lane = threadIdx.x & 63;
    const int la = lane & 31, hi = lane >> 5;

    for (;;) {
        if (threadIdx.x == 0) s_idx = atomicAdd(ctr + grp, 1u);
        __syncthreads();                     // publish s_idx; protect o_l reuse
        const unsigned int idx = s_idx;
        if (idx >= nit) return;
        const int h  = (int)((LH >> (8 * (idx >> 5))) & 0xFF);
        const int pr = (int)(idx & 31u);
        const int qt_hi = 63 - 2 * pr;       // pairs: (63,62),(61,60),...,(1,0)
        const int qt_lo = qt_hi - 1;
        const int bh = bat * 16 + h;
        const int qw_hi = qt_hi * 32;
        const int qw_lo = qw_hi - 32;
        const size_t tbh = (size_t)bh * 64;
        const float slope2 = alibi[(size_t)bh * SEQ + 1] * LOG2E;

        // Q fragments for both q-tiles
        const u16* qph = Qf + (tbh + qt_hi) * 2048 + lane * 8;
        bf16x8 qfh0 = *reinterpret_cast<const bf16x8*>(qph);
        bf16x8 qfh1 = *reinterpret_cast<const bf16x8*>(qph + 512);
        bf16x8 qfh2 = *reinterpret_cast<const bf16x8*>(qph + 1024);
        bf16x8 qfh3 = *reinterpret_cast<const bf16x8*>(qph + 1536);
        const u16* qpl = qph - 2048;
        bf16x8 qfl0 = *reinterpret_cast<const bf16x8*>(qpl);
        bf16x8 qfl1 = *reinterpret_cast<const bf16x8*>(qpl + 512);
        bf16x8 qfl2 = *reinterpret_cast<const bf16x8*>(qpl + 1024);
        bf16x8 qfl3 = *reinterpret_cast<const bf16x8*>(qpl + 1536);

        // hoisted first-tile K/V load
        const u16* kbase = Kf + tbh * 2048 + lane * 8;
        const u16* vbase = Vf + tbh * 2048 + lane * 8;
        const int t0 = qt_hi - wave;
        const int ta = (t0 >= 0) ? t0 : 0;
        bf16x8 ak0, ak1, ak2, ak3, av0, av1, av2, av3;
        bf16x8 bk0, bk1, bk2, bk3, bv0, bv1, bv2, bv3;
        LOADT(a, ta)

        // kb per side from precomputed norms
        const float* kp8 = knp + bh * 8;
        const float knv = fmaxf(fmaxf(fmaxf(kp8[0], kp8[1]), fmaxf(kp8[2], kp8[3])),
                                fmaxf(fmaxf(kp8[4], kp8[5]), fmaxf(kp8[6], kp8[7])));
        const float kb_h = qn[tbh + qt_hi] * knv * IN2;
        const float kb_l = qn[tbh + qt_lo] * knv * IN2;
        const float C0 = slope2 * (float)(4 * hi - la);

        // static windows; loop to t_min = min (extra tiles only add accurate terms)
        const float Wh = (47.f + 2.f * kb_h) / slope2;
        const float Wl = (47.f + 2.f * kb_l) / slope2;
        const int lo_kh = qw_hi - 31 - (int)Wh;
        const int lo_kl = qw_lo - 31 - (int)Wl;
        const int t_lh = lo_kh <= 0 ? 0 : ((lo_kh + 31) >> 5);
        const int t_ll = lo_kl <= 0 ? 0 : ((lo_kl + 31) >> 5);
        const int t_min = (t_lh < t_ll) ? t_lh : t_ll;

        f32x16 o0h = {}, o1h = {}, o0l = {}, o1l = {};
        float l_h = 0.f, l_l = 0.f;

        if (t0 >= t_min) {
            const int nit2 = ((t0 - t_min) >> 2) + 1;
            const int t1 = (nit2 > 1) ? t0 - 4 : t0;
            // peeled first iteration: flags by wave
            if (wave == 0)      { STEP2(a, b, t0, t1, 1, 0, 0) }   // hi diag, lo absent
            else if (wave == 1) { STEP2(a, b, t0, t1, 0, 1, 1) }   // lo diag
            else                { STEP2(a, b, t0, t1, 0, 1, 0) }
            int i = 1;
            while (i < nit2) {
                {
                    const int tc = t0 - 4 * i;
                    const int tn = (i + 1 < nit2) ? tc - 4 : tc;
                    STEP2(b, a, tc, tn, 0, 1, 0)
                }
                ++i;
                if (i >= nit2) break;
                {
                    const int tc = t0 - 4 * i;
                    const int tn = (i + 1 < nit2) ? tc - 4 : tc;
                    STEP2(a, b, tc, tn, 0, 1, 0)
                }
                ++i;
            }
        }

        const int qq = threadIdx.x >> 3;
        const int d0 = (threadIdx.x & 7) * 8;
        const int bb = bh >> 4, hh = bh & 15;

        // ---- combine HI ----
        l_h += __shfl_xor(l_h, 32);
        if (hi == 0) ml[wave][la] = l_h;
        #pragma unroll
        for (int r = 0; r < 16; ++r) {
            int d = (r & 3) + 8 * (r >> 2) + 4 * hi;
            o_l[wave][d][la]      = o0h[r];
            o_l[wave][d + 32][la] = o1h[r];
        }
        __syncthreads();
        {
            float L = ml[0][qq] + ml[1][qq] + ml[2][qq] + ml[3][qq];
            float inv = 1.0f / L;
            unsigned int packed[4];
            #pragma unroll
            for (int e2 = 0; e2 < 4; ++e2) {
                float Oa = o_l[0][d0 + 2 * e2][qq] + o_l[1][d0 + 2 * e2][qq]
                         + o_l[2][d0 + 2 * e2][qq] + o_l[3][d0 + 2 * e2][qq];
                float Ob = o_l[0][d0 + 2 * e2 + 1][qq] + o_l[1][d0 + 2 * e2 + 1][qq]
                         + o_l[2][d0 + 2 * e2 + 1][qq] + o_l[3][d0 + 2 * e2 + 1][qq];
                packed[e2] = (unsigned)f2bf(Oa * inv) | ((unsigned)f2bf(Ob * inv) << 16);
            }
            u32x4 pv; pv[0] = packed[0]; pv[1] = packed[1]; pv[2] = packed[2]; pv[3] = packed[3];
            *reinterpret_cast<u32x4*>(
                &ctx[((size_t)(bb * SEQ + qw_hi + qq)) * HIDDEN + hh * HEAD_DIM + d0]) = pv;
        }
        __syncthreads();   // all hi reads done before lo overwrites

        // ---- combine LO ----
        l_l += __shfl_xor(l_l, 32);
        if (hi == 0) ml[wave][la] = l_l;
        #pragma unroll
        for (int r = 0; r < 16; ++r) {
            int d = (r & 3) + 8 * (r >> 2) + 4 * hi;
            o_l[wave][d][la]      = o0l[r];
            o_l[wave][d + 32][la] = o1l[r];
        }
        __syncthreads();
        {
            float L = ml[0][qq] + ml[1][qq] + ml[2][qq] + ml[3][qq];
            float inv = 1.0f / L;
            unsigned int packed[4];
            #pragma unroll
            for (int e2 = 0; e2 < 4; ++e2) {
                float Oa = o_l[0][d0 + 2 * e2][qq] + o_l[1][d0 + 2 * e2][qq]
                         + o_l[2][d0 + 2 * e2][qq] + o_l[3][d0 + 2 * e2][qq];
                float Ob = o_l[0][d0 + 2 * e2 + 1][qq] + o_l[1][d0 + 2 * e2 + 1][qq]
                         + o_l[2][d0 + 2 * e2 + 1][qq] + o_l[3][d0 + 2 * e2 + 1][qq];
                packed[e2] = (unsigned)f2bf(Oa * inv) | ((unsigned)f2bf(Ob * inv) << 16);
            }
            u32x4 pv; pv[0] = packed[0]; pv[1] = packed[1]; pv[2] = packed[2]; pv[3] = packed[3];
            *reinterpret_cast<u32x4*>(
                &ctx[((size_t)(bb * SEQ + qw_lo + qq)) * HIDDEN + hh * HEAD_DIM + d0]) = pv;
        }
    }
}

extern "C" void kernel_launch(void* const* d_in, const int* in_sizes, int n_in,
                              void* d_out, int out_size, void* d_ws, size_t ws_size,
                              hipStream_t stream) {
    const float* x        = (const float*)d_in[0];
    const float* residual = (const float*)d_in[1];
    const float* alibi    = (const float*)d_in[2];
    const float* W_qkv    = (const float*)d_in[4];
    const float* b_qkv    = (const float*)d_in[5];
    const float* W_dense  = (const float*)d_in[6];
    const float* b_dense  = (const float*)d_in[7];
    float* out = (float*)d_out;

    char* ws = (char*)d_ws;
    u16* xb  = (u16*)(ws);                 //  8 MB  x bf16 fragment-major
    u16* wqb = (u16*)(ws + 8388608);       //  6 MB  W_qkv bf16 fragment-major
    u16* wdb = (u16*)(ws + 14680064);      //  2 MB  W_dense bf16 row-major
    u16* q   = (u16*)(ws + 16777216);      //  8 MB  fragment-major Q tiles
    u16* k   = (u16*)(ws + 25165824);      //  8 MB  fragment-major K tiles
    u16* vT  = (u16*)(ws + 33554432);      //  8 MB  fragment-major V tiles
    u16* ctx = (u16*)(ws + 41943040);      //  8 MB  [B*S][1024]
    float* knp = (float*)(ws + 50331648);  //  1 KB  per-(bh,slice) max ||k||
    float* qn  = (float*)(ws + 50331648 + 1024);   // 8 KB per-(bh,qt) max ||q||
    unsigned int* ctr = (unsigned int*)(ws + 50331648 + 16384);  // 8 group counters

    cvt_all<<<4096, 256, 0, stream>>>(x, W_qkv, W_dense, xb, wqb, wdb);
    gemm_qkv<<<768, 256, 0, stream>>>(xb, wqb, b_qkv, q, k, vT);
    norms<<<256, 256, 0, stream>>>(k, q, knp, qn, ctr);
    attn<<<512, 256, 0, stream>>>(q, k, vT, alibi, knp, qn, ctx, ctr);
    gemm_dense<<<512, 256, 0, stream>>>(ctx, wdb, b_dense, residual, out);
}

// Round 29
// 113.871 us; speedup vs baseline: 1.1169x; 1.0328x over previous
//
#include <hip/hip_runtime.h>
#include <hip/hip_bf16.h>

#define NUM_HEADS 16
#define HEAD_DIM  64
#define HIDDEN    1024
#define BATCH     2
#define SEQ       2048
#define K_DIM     1024
#define INV_NORM  0.125f
#define LOG2E     1.4426950408889634f
#define IN2       (INV_NORM * LOG2E)

typedef __attribute__((ext_vector_type(4)))  float f32x4;
typedef __attribute__((ext_vector_type(16))) float f32x16;
typedef __attribute__((ext_vector_type(8)))  short bf16x8;
typedef __attribute__((ext_vector_type(4)))  unsigned int u32x4;
typedef __attribute__((ext_vector_type(2)))  unsigned int u32x2;
typedef unsigned short u16;

__device__ inline u16 f2bf(float f) {
    __hip_bfloat16 h = __float2bfloat16(f);
    return __builtin_bit_cast(u16, h);
}
__device__ inline float bf2f(u16 u) {
    unsigned int v = ((unsigned int)u) << 16;
    return __builtin_bit_cast(float, v);
}

__device__ inline f32x16 mfma32(bf16x8 a, bf16x8 b, f32x16 c) {
    return __builtin_amdgcn_mfma_f32_32x32x16_bf16(a, b, c, 0, 0, 0);
}

// async global->LDS, 16B per lane (used by gemm_dense only)
__device__ inline void gl_lds16(const u16* g, u16* s) {
    __builtin_amdgcn_global_load_lds(
        (const __attribute__((address_space(1))) unsigned int*)g,
        (__attribute__((address_space(3))) unsigned int*)s, 16, 0, 0);
}

// ---------------- cvt + pack: x,W_qkv -> fragment-major bf16; W_dense -> row-major ----------------
__device__ inline void pack8(const float* src, u16* dst) {
    const float4 v0 = *reinterpret_cast<const float4*>(src);
    const float4 v1 = *reinterpret_cast<const float4*>(src + 4);
    ushort4 o0, o1;
    o0.x = f2bf(v0.x); o0.y = f2bf(v0.y); o0.z = f2bf(v0.z); o0.w = f2bf(v0.w);
    o1.x = f2bf(v1.x); o1.y = f2bf(v1.y); o1.z = f2bf(v1.z); o1.w = f2bf(v1.w);
    *reinterpret_cast<ushort4*>(dst)     = o0;
    *reinterpret_cast<ushort4*>(dst + 4) = o1;
}
__global__ __launch_bounds__(256) void cvt_all(
        const float* __restrict__ x, const float* __restrict__ wq,
        const float* __restrict__ wd,
        u16* __restrict__ xb, u16* __restrict__ wqb, u16* __restrict__ wdb) {
    int t = blockIdx.x * 256 + threadIdx.x;   // 1048576 threads, 8 elem each
    if (t < 524288) {            // x: 4096 rows -> 128 m-tiles
        int mt = t >> 12, rem = t & 4095;
        int kblk = rem >> 6, hf = (rem >> 5) & 1, ra = rem & 31;
        pack8(x + ((size_t)(mt * 32 + ra)) * K_DIM + kblk * 16 + hf * 8,
              xb + (size_t)t * 8);
    } else if (t < 917504) {     // W_qkv: 3072 rows -> 96 tiles
        int t2 = t - 524288;
        int nt = t2 >> 12, rem = t2 & 4095;
        int kblk = rem >> 6, hf = (rem >> 5) & 1, ra = rem & 31;
        pack8(wq + ((size_t)(nt * 32 + ra)) * K_DIM + kblk * 16 + hf * 8,
              wqb + (size_t)t2 * 8);
    } else {                     // W_dense: plain row-major
        int i = (t - 917504) * 8;
        pack8(wd + i, wdb + i);
    }
}

// ---------------- QKV GEMM: LDS-free loads + LDS-staged coalesced epilogue ----------------
#define QLOAD(P, kb) {                                                        \
    P##x0 = *reinterpret_cast<const bf16x8*>(pa0 + (size_t)(kb) * 512);       \
    P##x1 = *reinterpret_cast<const bf16x8*>(pa1 + (size_t)(kb) * 512);       \
    P##y0 = *reinterpret_cast<const bf16x8*>(pb0 + (size_t)(kb) * 512);       \
    P##y1 = *reinterpret_cast<const bf16x8*>(pb1 + (size_t)(kb) * 512);       \
    P##x2 = *reinterpret_cast<const bf16x8*>(pa0 + (size_t)(kb + 1) * 512);   \
    P##x3 = *reinterpret_cast<const bf16x8*>(pa1 + (size_t)(kb + 1) * 512);   \
    P##y2 = *reinterpret_cast<const bf16x8*>(pb0 + (size_t)(kb + 1) * 512);   \
    P##y3 = *reinterpret_cast<const bf16x8*>(pb1 + (size_t)(kb + 1) * 512);   \
}
#define QSTEP(P) {                                                            \
    acc[0][0] = mfma32(P##x0, P##y0, acc[0][0]);                              \
    acc[0][1] = mfma32(P##x0, P##y1, acc[0][1]);                              \
    acc[1][0] = mfma32(P##x1, P##y0, acc[1][0]);                              \
    acc[1][1] = mfma32(P##x1, P##y1, acc[1][1]);                              \
    acc[0][0] = mfma32(P##x2, P##y2, acc[0][0]);                              \
    acc[0][1] = mfma32(P##x2, P##y3, acc[0][1]);                              \
    acc[1][0] = mfma32(P##x3, P##y2, acc[1][0]);                              \
    acc[1][1] = mfma32(P##x3, P##y3, acc[1][1]);                              \
}
__global__ __launch_bounds__(256) void gemm_qkv(
        const u16* __restrict__ Af, const u16* __restrict__ Bf,
        const float* __restrict__ bias,
        u16* __restrict__ qo, u16* __restrict__ ko2, u16* __restrict__ vTo) {
    __shared__ u16 st[4][2][2048];   // per-wave 2x4KB staging (epilogue only)
    int lin = blockIdx.x;
    int g = lin & 7, i2 = lin >> 3;           // i2: 0..95
    const int mblk = ((g & 3) * 8 + (i2 & 7)) * 128;
    const int nblk = ((g >> 2) * 12 + (i2 >> 3)) * 128;
    const int tid = threadIdx.x;
    const int w = tid >> 6, lane = tid & 63;
    const int la = lane & 31, hi = lane >> 5;
    const int wr = w >> 1, wc = w & 1;
    const int mt0 = (mblk >> 5) + wr * 2;
    const int nt0 = (nblk >> 5) + wc * 2;
    const u16* pa0 = Af + (size_t)mt0 * 64 * 512 + lane * 8;
    const u16* pa1 = pa0 + 64 * 512;
    const u16* pb0 = Bf + (size_t)nt0 * 64 * 512 + lane * 8;
    const u16* pb1 = pb0 + 64 * 512;
    f32x16 acc[2][2] = {};
    bf16x8 ax0, ax1, ax2, ax3, ay0, ay1, ay2, ay3;
    bf16x8 bx0, bx1, bx2, bx3, by0, by1, by2, by3;
    QLOAD(a, 0)
    #pragma unroll 4
    for (int kb = 0; kb < 64; kb += 4) {
        const int n1 = (kb + 2 < 62) ? kb + 2 : 62;
        QLOAD(b, n1)
        QSTEP(a)
        const int n2 = (kb + 4 < 62) ? kb + 4 : 62;
        QLOAD(a, n2)
        QSTEP(b)
    }
    // ---- epilogue: scatter into LDS (cheap), then linear coalesced global copy ----
    // Wave's 64-col span is 64-aligned -> one (tensor, head); 64 rows -> 2 full 4KB tiles.
    const int c0 = nblk + wc * 64;
    const int seg = c0 >> 6;                 // 0..47
    const int h = seg / 3, which = seg % 3;  // wave-uniform
    const int mrow0 = mblk + wr * 64;
    const int bb = mrow0 >> 11;
    const int bh = bb * NUM_HEADS + h;
    const int tglob0 = (mrow0 & (SEQ - 1)) >> 5;
    u16* dstbase = (which == 0 ? qo : which == 1 ? ko2 : vTo)
                 + ((size_t)(bh * 64 + tglob0)) * 2048;
    u16* myst = &st[w][0][0];
    #pragma unroll
    for (int mi = 0; mi < 2; ++mi)
    #pragma unroll
    for (int ni = 0; ni < 2; ++ni) {
        const int d = ni * 32 + la;
        const float bv = bias[c0 + ni * 32 + la];
        #pragma unroll
        for (int r = 0; r < 16; ++r) {
            const int srow = (r & 3) + 8 * (r >> 2) + 4 * hi;   // row within 32-tile
            const u16 o = f2bf(acc[mi][ni][r] + bv);
            int off;
            if (which == 2)   // v: ra from d, (ks,hf,e) from row
                off = ((d >> 5) * 2 + (srow >> 4)) * 512 + ((srow >> 3) & 1) * 256
                    + (d & 31) * 8 + (srow & 7);
            else              // q/k: (kk,hf,e) from d, ra from row
                off = (d >> 4) * 512 + ((d >> 3) & 1) * 256 + srow * 8 + (d & 7);
            myst[mi * 2048 + off] = o;
        }
    }
    asm volatile("s_waitcnt lgkmcnt(0)" ::: "memory");   // wave-local LDS drain
    #pragma unroll
    for (int i = 0; i < 8; ++i) {            // 8KB/wave, 128B/lane, fully coalesced
        const int eo = i * 512 + lane * 8;
        *reinterpret_cast<u32x4*>(dstbase + eo) =
            *reinterpret_cast<const u32x4*>(myst + eo);
    }
}

// ---------------- Dense GEMM + bias + residual: 64x128 tile, 512 blocks (2/CU) ----------------
__global__ __launch_bounds__(256) void gemm_dense(
        const u16* __restrict__ A, const u16* __restrict__ W,
        const float* __restrict__ bias, const float* __restrict__ residual,
        float* __restrict__ out) {
    __shared__ u16 As[64 * 64];
    __shared__ u16 Bs[128 * 64];
    int lin = blockIdx.x;
    int g = lin & 7, i2 = lin >> 3;           // i2: 0..63
    const int mblk = (g * 8 + (i2 & 7)) * 64;
    const int nblk = (i2 >> 3) * 128;
    const int tid = threadIdx.x;
    const int w = tid >> 6, l = tid & 63;
    const int la = l & 31, hi = l >> 5;
    const int wr = w & 1, wc = w >> 1;
    const int kperm = (((l & 7) ^ (l >> 3)) << 3);
    const u16* gA = A + (size_t)(mblk + w * 16 + (l >> 3)) * K_DIM + kperm;
    const u16* gB = W + (size_t)(nblk + w * 32 + (l >> 3)) * K_DIM + kperm;
    const int sca = (la & 7) << 3;
    f32x16 acc2[2] = {};
    for (int kt = 0; kt < 16; ++kt) {
        const int ko = kt * 64;
        gl_lds16(gA + ko,              &As[(w * 16) * 64]);
        gl_lds16(gA + ko + 8 * K_DIM,  &As[(w * 16 + 8) * 64]);
        #pragma unroll
        for (int i = 0; i < 4; ++i)
            gl_lds16(gB + i * 8 * K_DIM + ko, &Bs[(w * 32 + i * 8) * 64]);
        asm volatile("s_waitcnt vmcnt(0)" ::: "memory");
        __syncthreads();
        const u16* pA = &As[(wr * 32 + la) * 64];
        const u16* pB = &Bs[(wc * 64 + la) * 64];
        #pragma unroll
        for (int kk = 0; kk < 4; ++kk) {
            const int co = (kk * 16 + hi * 8) ^ sca;
            bf16x8 a0 = *reinterpret_cast<const bf16x8*>(pA + co);
            bf16x8 b0 = *reinterpret_cast<const bf16x8*>(pB + co);
            bf16x8 b1 = *reinterpret_cast<const bf16x8*>(pB + 32 * 64 + co);
            acc2[0] = mfma32(a0, b0, acc2[0]);
            acc2[1] = mfma32(a0, b1, acc2[1]);
        }
        __syncthreads();
    }
    #pragma unroll
    for (int ni = 0; ni < 2; ++ni) {
        int c = nblk + wc * 64 + ni * 32 + la;
        float bv = bias[c];
        #pragma unroll
        for (int r = 0; r < 16; ++r) {
            int m = mblk + wr * 32 + (r & 3) + 8 * (r >> 2) + 4 * hi;
            out[(size_t)m * HIDDEN + c] = acc2[ni][r] + bv + residual[(size_t)m * HIDDEN + c];
        }
    }
}

// ---------------- norms: per-(bh,slice) max ||k|| partials + per-(bh,qt) max ||q|| ----------------
__global__ __launch_bounds__(256) void norms(
        const u16* __restrict__ Kf, const u16* __restrict__ Qf,
        float* __restrict__ knp, float* __restrict__ qn,
        unsigned int* __restrict__ ctr) {
    if (blockIdx.x == 0 && threadIdx.x < 8) ctr[threadIdx.x] = 0;  // stream-ordered
    __shared__ float red[256];
    const int bh = blockIdx.x >> 3;
    const int s  = (blockIdx.x & 7) * 256 + threadIdx.x;    // one row per thread
    const size_t tb = ((size_t)(bh * 64 + (s >> 5))) * 2048 + (s & 31) * 8;
    float ssk = 0.f, ssq = 0.f;
    #pragma unroll
    for (int kk = 0; kk < 4; ++kk)
    #pragma unroll
    for (int hf = 0; hf < 2; ++hf) {
        bf16x8 v = *reinterpret_cast<const bf16x8*>(Kf + tb + kk * 512 + hf * 256);
        bf16x8 u = *reinterpret_cast<const bf16x8*>(Qf + tb + kk * 512 + hf * 256);
        #pragma unroll
        for (int e = 0; e < 8; ++e) {
            float fk = bf2f((u16)v[e]);
            float fq = bf2f((u16)u[e]);
            ssk = fmaf(fk, fk, ssk);
            ssq = fmaf(fq, fq, ssq);
        }
    }
    float mq = ssq;
    #pragma unroll
    for (int off = 1; off <= 16; off <<= 1) mq = fmaxf(mq, __shfl_xor(mq, off));
    if ((threadIdx.x & 31) == 0)
        qn[(size_t)bh * 64 + (s >> 5)] = sqrtf(mq);
    red[threadIdx.x] = ssk;
    __syncthreads();
    for (int off = 128; off; off >>= 1) {
        if (threadIdx.x < (unsigned)off)
            red[threadIdx.x] = fmaxf(red[threadIdx.x], red[threadIdx.x + off]);
        __syncthreads();
    }
    if (threadIdx.x == 0) knp[blockIdx.x] = sqrtf(red[0]);
}

// ---------------- Flash attention: dual-q-tile items (2 chains/wave) ----------------
#define LOADT(P, tt) {                                                        \
    const u16* kp_ = kbase + (size_t)(tt) * 2048;                             \
    P##k0 = *reinterpret_cast<const bf16x8*>(kp_);                            \
    P##k1 = *reinterpret_cast<const bf16x8*>(kp_ + 512);                      \
    P##k2 = *reinterpret_cast<const bf16x8*>(kp_ + 1024);                     \
    P##k3 = *reinterpret_cast<const bf16x8*>(kp_ + 1536);                     \
    const u16* vp_ = vbase + (size_t)(tt) * 2048;                             \
    P##v0 = *reinterpret_cast<const bf16x8*>(vp_);                            \
    P##v1 = *reinterpret_cast<const bf16x8*>(vp_ + 512);                      \
    P##v2 = *reinterpret_cast<const bf16x8*>(vp_ + 1024);                     \
    P##v3 = *reinterpret_cast<const bf16x8*>(vp_ + 1536);                     \
}

// softmax + PV for one side given score regs SA/SB, per-side base, accumulators
#define SMPV(SA, SB, BASEX, DIAGX, LI, OA, OB, P) {                           \
    float p_[16];                                                             \
    _Pragma("unroll")                                                         \
    for (int r = 0; r < 16; ++r) {                                            \
        const float cst_ = (float)((r & 3) + 8 * (r >> 2));                   \
        p_[r] = __builtin_amdgcn_exp2f(                                       \
            fmaf(SA[r] + SB[r], IN2, fmaf(cst_, slope2, BASEX)));             \
    }                                                                         \
    if (DIAGX) {                                                              \
        _Pragma("unroll")                                                     \
        for (int r = 0; r < 16; ++r) {                                        \
            int kr_ = (r & 3) + 8 * (r >> 2) + 4 * hi;                        \
            if (kr_ > la) p_[r] = 0.f;                                        \
        }                                                                     \
    }                                                                         \
    LI += ((p_[0] + p_[1]) + (p_[2] + p_[3])) + ((p_[4] + p_[5]) + (p_[6] + p_[7]))   \
        + ((p_[8] + p_[9]) + (p_[10] + p_[11])) + ((p_[12] + p_[13]) + (p_[14] + p_[15])); \
    unsigned pk_[8];                                                          \
    _Pragma("unroll")                                                         \
    for (int m = 0; m < 4; ++m) {                                             \
        unsigned b0_ = __builtin_bit_cast(unsigned, p_[4 * m])     + 0x8000u; \
        unsigned b1_ = __builtin_bit_cast(unsigned, p_[4 * m + 1]) + 0x8000u; \
        unsigned b2_ = __builtin_bit_cast(unsigned, p_[4 * m + 2]) + 0x8000u; \
        unsigned b3_ = __builtin_bit_cast(unsigned, p_[4 * m + 3]) + 0x8000u; \
        pk_[2 * m]     = __builtin_amdgcn_perm(b1_, b0_, 0x07060302u);        \
        pk_[2 * m + 1] = __builtin_amdgcn_perm(b3_, b2_, 0x07060302u);        \
    }                                                                         \
    u32x2 r0_ = __builtin_amdgcn_permlane32_swap(pk_[0], pk_[2], false, false); \
    u32x2 r1_ = __builtin_amdgcn_permlane32_swap(pk_[1], pk_[3], false, false); \
    u32x2 r2_ = __builtin_amdgcn_permlane32_swap(pk_[4], pk_[6], false, false); \
    u32x2 r3_ = __builtin_amdgcn_permlane32_swap(pk_[5], pk_[7], false, false); \
    u32x4 pb0_, pb1_;                                                         \
    pb0_[0] = r0_[0]; pb0_[1] = r1_[0]; pb0_[2] = r0_[1]; pb0_[3] = r1_[1];   \
    pb1_[0] = r2_[0]; pb1_[1] = r3_[0]; pb1_[2] = r2_[1]; pb1_[3] = r3_[1];   \
    bf16x8 pf0_ = __builtin_bit_cast(bf16x8, pb0_);                           \
    bf16x8 pf1_ = __builtin_bit_cast(bf16x8, pb1_);                           \
    OA = mfma32(P##v0, pf0_, OA);                                             \
    OA = mfma32(P##v1, pf1_, OA);                                             \
    OB = mfma32(P##v2, pf0_, OB);                                             \
    OB = mfma32(P##v3, pf1_, OB);                                             \
}

#define STEP2(P, N, tcur, tnxt, DIAGH, DOLO, DIAGL) {                         \
    const int k0_ = (tcur) * 32;                                              \
    f32x16 sha_ = {}, shb_ = {};                                              \
    sha_ = mfma32(P##k0, qfh0, sha_);                                         \
    shb_ = mfma32(P##k1, qfh1, shb_);                                         \
    sha_ = mfma32(P##k2, qfh2, sha_);                                         \
    shb_ = mfma32(P##k3, qfh3, shb_);                                         \
    f32x16 sla_ = {}, slb_ = {};                                              \
    if (DOLO) {                                                               \
        sla_ = mfma32(P##k0, qfl0, sla_);                                     \
        slb_ = mfma32(P##k1, qfl1, slb_);                                     \
        sla_ = mfma32(P##k2, qfl2, sla_);                                     \
        slb_ = mfma32(P##k3, qfl3, slb_);                                     \
    }                                                                         \
    LOADT(N, tnxt)                                                            \
    {                                                                         \
        const float baseh_ = fmaf(slope2, (float)(k0_ - qw_hi), C0 - kb_h);   \
        SMPV(sha_, shb_, baseh_, DIAGH, l_h, o0h, o1h, P)                     \
    }                                                                         \
    if (DOLO) {                                                               \
        const float basel_ = fmaf(slope2, (float)(k0_ - qw_lo), C0 - kb_l);   \
        SMPV(sla_, slb_, basel_, DIAGL, l_l, o0l, o1l, P)                     \
    }                                                                         \
}

__global__ __launch_bounds__(256) void attn(
        const u16* __restrict__ Qf, const u16* __restrict__ Kf,
        const u16* __restrict__ Vf, const float* __restrict__ alibi,
        const float* __restrict__ knp, const float* __restrict__ qn,
        u16* __restrict__ ctx, unsigned int* __restrict__ ctr) {
    __shared__ float o_l[4][64][33];
    __shared__ float ml[4][32];
    __shared__ unsigned int s_idx;
    const int grp  = blockIdx.x & 7;
    const int lst  = grp >> 1;
    const int bat  = grp & 1;
    // packed bh-head lists (byte j = head of slot j); 32 qt-pairs per slot
    const unsigned long long LH = (lst == 0) ? 0x0000000007080Full
                               : (lst == 1) ? 0x000000000006090Eull
                               : (lst == 2) ? 0x0000000003050A0Dull
                                            : 0x00000102040B0Cull;
    const unsigned nit = (lst == 0) ? 96u : (lst == 3) ? 160u : 128u;
    const int wave = __builtin_amdgcn_readfirstlane(threadIdx.x >> 6);  // SGPR
    const int lane = threadIdx.x & 63;
    const int la = lane & 31, hi = lane >> 5;

    for (;;) {
        if (threadIdx.x == 0) s_idx = atomicAdd(ctr + grp, 1u);
        __syncthreads();                     // publish s_idx; protect o_l reuse
        const unsigned int idx = s_idx;
        if (idx >= nit) return;
        const int h  = (int)((LH >> (8 * (idx >> 5))) & 0xFF);
        const int pr = (int)(idx & 31u);
        const int qt_hi = 63 - 2 * pr;       // pairs: (63,62),(61,60),...,(1,0)
        const int qt_lo = qt_hi - 1;
        const int bh = bat * 16 + h;
        const int qw_hi = qt_hi * 32;
        const int qw_lo = qw_hi - 32;
        const size_t tbh = (size_t)bh * 64;
        const float slope2 = alibi[(size_t)bh * SEQ + 1] * LOG2E;

        // Q fragments for both q-tiles
        const u16* qph = Qf + (tbh + qt_hi) * 2048 + lane * 8;
        bf16x8 qfh0 = *reinterpret_cast<const bf16x8*>(qph);
        bf16x8 qfh1 = *reinterpret_cast<const bf16x8*>(qph + 512);
        bf16x8 qfh2 = *reinterpret_cast<const bf16x8*>(qph + 1024);
        bf16x8 qfh3 = *reinterpret_cast<const bf16x8*>(qph + 1536);
        const u16* qpl = qph - 2048;
        bf16x8 qfl0 = *reinterpret_cast<const bf16x8*>(qpl);
        bf16x8 qfl1 = *reinterpret_cast<const bf16x8*>(qpl + 512);
        bf16x8 qfl2 = *reinterpret_cast<const bf16x8*>(qpl + 1024);
        bf16x8 qfl3 = *reinterpret_cast<const bf16x8*>(qpl + 1536);

        // hoisted first-tile K/V load
        const u16* kbase = Kf + tbh * 2048 + lane * 8;
        const u16* vbase = Vf + tbh * 2048 + lane * 8;
        const int t0 = qt_hi - wave;
        const int ta = (t0 >= 0) ? t0 : 0;
        bf16x8 ak0, ak1, ak2, ak3, av0, av1, av2, av3;
        bf16x8 bk0, bk1, bk2, bk3, bv0, bv1, bv2, bv3;
        LOADT(a, ta)

        // kb per side from precomputed norms
        const float* kp8 = knp + bh * 8;
        const float knv = fmaxf(fmaxf(fmaxf(kp8[0], kp8[1]), fmaxf(kp8[2], kp8[3])),
                                fmaxf(fmaxf(kp8[4], kp8[5]), fmaxf(kp8[6], kp8[7])));
        const float kb_h = qn[tbh + qt_hi] * knv * IN2;
        const float kb_l = qn[tbh + qt_lo] * knv * IN2;
        const float C0 = slope2 * (float)(4 * hi - la);

        // static windows; loop to t_min = min (extra tiles only add accurate terms)
        const float Wh = (47.f + 2.f * kb_h) / slope2;
        const float Wl = (47.f + 2.f * kb_l) / slope2;
        const int lo_kh = qw_hi - 31 - (int)Wh;
        const int lo_kl = qw_lo - 31 - (int)Wl;
        const int t_lh = lo_kh <= 0 ? 0 : ((lo_kh + 31) >> 5);
        const int t_ll = lo_kl <= 0 ? 0 : ((lo_kl + 31) >> 5);
        const int t_min = (t_lh < t_ll) ? t_lh : t_ll;

        f32x16 o0h = {}, o1h = {}, o0l = {}, o1l = {};
        float l_h = 0.f, l_l = 0.f;

        if (t0 >= t_min) {
            const int nit2 = ((t0 - t_min) >> 2) + 1;
            const int t1 = (nit2 > 1) ? t0 - 4 : t0;
            // peeled first iteration: flags by wave
            if (wave == 0)      { STEP2(a, b, t0, t1, 1, 0, 0) }   // hi diag, lo absent
            else if (wave == 1) { STEP2(a, b, t0, t1, 0, 1, 1) }   // lo diag
            else                { STEP2(a, b, t0, t1, 0, 1, 0) }
            int i = 1;
            while (i < nit2) {
                {
                    const int tc = t0 - 4 * i;
                    const int tn = (i + 1 < nit2) ? tc - 4 : tc;
                    STEP2(b, a, tc, tn, 0, 1, 0)
                }
                ++i;
                if (i >= nit2) break;
                {
                    const int tc = t0 - 4 * i;
                    const int tn = (i + 1 < nit2) ? tc - 4 : tc;
                    STEP2(a, b, tc, tn, 0, 1, 0)
                }
                ++i;
            }
        }

        const int qq = threadIdx.x >> 3;
        const int d0 = (threadIdx.x & 7) * 8;
        const int bb = bh >> 4, hh = bh & 15;

        // ---- combine HI ----
        l_h += __shfl_xor(l_h, 32);
        if (hi == 0) ml[wave][la] = l_h;
        #pragma unroll
        for (int r = 0; r < 16; ++r) {
            int d = (r & 3) + 8 * (r >> 2) + 4 * hi;
            o_l[wave][d][la]      = o0h[r];
            o_l[wave][d + 32][la] = o1h[r];
        }
        __syncthreads();
        {
            float L = ml[0][qq] + ml[1][qq] + ml[2][qq] + ml[3][qq];
            float inv = 1.0f / L;
            unsigned int packed[4];
            #pragma unroll
            for (int e2 = 0; e2 < 4; ++e2) {
                float Oa = o_l[0][d0 + 2 * e2][qq] + o_l[1][d0 + 2 * e2][qq]
                         + o_l[2][d0 + 2 * e2][qq] + o_l[3][d0 + 2 * e2][qq];
                float Ob = o_l[0][d0 + 2 * e2 + 1][qq] + o_l[1][d0 + 2 * e2 + 1][qq]
                         + o_l[2][d0 + 2 * e2 + 1][qq] + o_l[3][d0 + 2 * e2 + 1][qq];
                packed[e2] = (unsigned)f2bf(Oa * inv) | ((unsigned)f2bf(Ob * inv) << 16);
            }
            u32x4 pv; pv[0] = packed[0]; pv[1] = packed[1]; pv[2] = packed[2]; pv[3] = packed[3];
            *reinterpret_cast<u32x4*>(
                &ctx[((size_t)(bb * SEQ + qw_hi + qq)) * HIDDEN + hh * HEAD_DIM + d0]) = pv;
        }
        __syncthreads();   // all hi reads done before lo overwrites

        // ---- combine LO ----
        l_l += __shfl_xor(l_l, 32);
        if (hi == 0) ml[wave][la] = l_l;
        #pragma unroll
        for (int r = 0; r < 16; ++r) {
            int d = (r & 3) + 8 * (r >> 2) + 4 * hi;
            o_l[wave][d][la]      = o0l[r];
            o_l[wave][d + 32][la] = o1l[r];
        }
        __syncthreads();
        {
            float L = ml[0][qq] + ml[1][qq] + ml[2][qq] + ml[3][qq];
            float inv = 1.0f / L;
            unsigned int packed[4];
            #pragma unroll
            for (int e2 = 0; e2 < 4; ++e2) {
                float Oa = o_l[0][d0 + 2 * e2][qq] + o_l[1][d0 + 2 * e2][qq]
                         + o_l[2][d0 + 2 * e2][qq] + o_l[3][d0 + 2 * e2][qq];
                float Ob = o_l[0][d0 + 2 * e2 + 1][qq] + o_l[1][d0 + 2 * e2 + 1][qq]
                         + o_l[2][d0 + 2 * e2 + 1][qq] + o_l[3][d0 + 2 * e2 + 1][qq];
                packed[e2] = (unsigned)f2bf(Oa * inv) | ((unsigned)f2bf(Ob * inv) << 16);
            }
            u32x4 pv; pv[0] = packed[0]; pv[1] = packed[1]; pv[2] = packed[2]; pv[3] = packed[3];
            *reinterpret_cast<u32x4*>(
                &ctx[((size_t)(bb * SEQ + qw_lo + qq)) * HIDDEN + hh * HEAD_DIM + d0]) = pv;
        }
    }
}

extern "C" void kernel_launch(void* const* d_in, const int* in_sizes, int n_in,
                              void* d_out, int out_size, void* d_ws, size_t ws_size,
                              hipStream_t stream) {
    const float* x        = (const float*)d_in[0];
    const float* residual = (const float*)d_in[1];
    const float* alibi    = (const float*)d_in[2];
    const float* W_qkv    = (const float*)d_in[4];
    const float* b_qkv    = (const float*)d_in[5];
    const float* W_dense  = (const float*)d_in[6];
    const float* b_dense  = (const float*)d_in[7];
    float* out = (float*)d_out;

    char* ws = (char*)d_ws;
    u16* xb  = (u16*)(ws);                 //  8 MB  x bf16 fragment-major
    u16* wqb = (u16*)(ws + 8388608);       //  6 MB  W_qkv bf16 fragment-major
    u16* wdb = (u16*)(ws + 14680064);      //  2 MB  W_dense bf16 row-major
    u16* q   = (u16*)(ws + 16777216);      //  8 MB  fragment-major Q tiles
    u16* k   = (u16*)(ws + 25165824);      //  8 MB  fragment-major K tiles
    u16* vT  = (u16*)(ws + 33554432);      //  8 MB  fragment-major V tiles
    u16* ctx = (u16*)(ws + 41943040);      //  8 MB  [B*S][1024]
    float* knp = (float*)(ws + 50331648);  //  1 KB  per-(bh,slice) max ||k||
    float* qn  = (float*)(ws + 50331648 + 1024);   // 8 KB per-(bh,qt) max ||q||
    unsigned int* ctr = (unsigned int*)(ws + 50331648 + 16384);  // 8 group counters

    cvt_all<<<4096, 256, 0, stream>>>(x, W_qkv, W_dense, xb, wqb, wdb);
    gemm_qkv<<<768, 256, 0, stream>>>(xb, wqb, b_qkv, q, k, vT);
    norms<<<256, 256, 0, stream>>>(k, q, knp, qn, ctr);
    attn<<<512, 256, 0, stream>>>(q, k, vT, alibi, knp, qn, ctx, ctr);
    gemm_dense<<<512, 256, 0, stream>>>(ctx, wdb, b_dense, residual, out);
}

// Round 30
// 107.127 us; speedup vs baseline: 1.1872x; 1.0629x over previous
//
#include <hip/hip_runtime.h>
#include <hip/hip_bf16.h>

#define NUM_HEADS 16
#define HEAD_DIM  64
#define HIDDEN    1024
#define BATCH     2
#define SEQ       2048
#define K_DIM     1024
#define INV_NORM  0.125f
#define LOG2E     1.4426950408889634f
#define IN2       (INV_NORM * LOG2E)

typedef __attribute__((ext_vector_type(4)))  float f32x4;
typedef __attribute__((ext_vector_type(16))) float f32x16;
typedef __attribute__((ext_vector_type(8)))  short bf16x8;
typedef __attribute__((ext_vector_type(4)))  unsigned int u32x4;
typedef __attribute__((ext_vector_type(2)))  unsigned int u32x2;
typedef unsigned short u16;

__device__ inline u16 f2bf(float f) {
    __hip_bfloat16 h = __float2bfloat16(f);
    return __builtin_bit_cast(u16, h);
}
__device__ inline float bf2f(u16 u) {
    unsigned int v = ((unsigned int)u) << 16;
    return __builtin_bit_cast(float, v);
}

__device__ inline f32x16 mfma32(bf16x8 a, bf16x8 b, f32x16 c) {
    return __builtin_amdgcn_mfma_f32_32x32x16_bf16(a, b, c, 0, 0, 0);
}

// async global->LDS, 16B per lane (used by gemm_dense only)
__device__ inline void gl_lds16(const u16* g, u16* s) {
    __builtin_amdgcn_global_load_lds(
        (const __attribute__((address_space(1))) unsigned int*)g,
        (__attribute__((address_space(3))) unsigned int*)s, 16, 0, 0);
}

// ---------------- cvt + pack; also zero norm/ctr scratch (stream-ordered before qkv) ----------------
__device__ inline void pack8(const float* src, u16* dst) {
    const float4 v0 = *reinterpret_cast<const float4*>(src);
    const float4 v1 = *reinterpret_cast<const float4*>(src + 4);
    ushort4 o0, o1;
    o0.x = f2bf(v0.x); o0.y = f2bf(v0.y); o0.z = f2bf(v0.z); o0.w = f2bf(v0.w);
    o1.x = f2bf(v1.x); o1.y = f2bf(v1.y); o1.z = f2bf(v1.z); o1.w = f2bf(v1.w);
    *reinterpret_cast<ushort4*>(dst)     = o0;
    *reinterpret_cast<ushort4*>(dst + 4) = o1;
}
__global__ __launch_bounds__(256) void cvt_all(
        const float* __restrict__ x, const float* __restrict__ wq,
        const float* __restrict__ wd,
        u16* __restrict__ xb, u16* __restrict__ wqb, u16* __restrict__ wdb,
        float* __restrict__ nrm, unsigned int* __restrict__ ctr) {
    if (blockIdx.x == 0) {
        for (int i = threadIdx.x; i < 2304; i += 256) nrm[i] = 0.f;   // knp2(256)+qn2(2048)
        if (threadIdx.x < 8) ctr[threadIdx.x] = 0u;
    }
    int t = blockIdx.x * 256 + threadIdx.x;   // 1048576 threads, 8 elem each
    if (t < 524288) {            // x: 4096 rows -> 128 m-tiles
        int mt = t >> 12, rem = t & 4095;
        int kblk = rem >> 6, hf = (rem >> 5) & 1, ra = rem & 31;
        pack8(x + ((size_t)(mt * 32 + ra)) * K_DIM + kblk * 16 + hf * 8,
              xb + (size_t)t * 8);
    } else if (t < 917504) {     // W_qkv: 3072 rows -> 96 tiles
        int t2 = t - 524288;
        int nt = t2 >> 12, rem = t2 & 4095;
        int kblk = rem >> 6, hf = (rem >> 5) & 1, ra = rem & 31;
        pack8(wq + ((size_t)(nt * 32 + ra)) * K_DIM + kblk * 16 + hf * 8,
              wqb + (size_t)t2 * 8);
    } else {                     // W_dense: plain row-major
        int i = (t - 917504) * 8;
        pack8(wd + i, wdb + i);
    }
}

// ---------------- QKV GEMM: LDS-free loads + LDS epilogue + fused norms ----------------
#define QLOAD(P, kb) {                                                        \
    P##x0 = *reinterpret_cast<const bf16x8*>(pa0 + (size_t)(kb) * 512);       \
    P##x1 = *reinterpret_cast<const bf16x8*>(pa1 + (size_t)(kb) * 512);       \
    P##y0 = *reinterpret_cast<const bf16x8*>(pb0 + (size_t)(kb) * 512);       \
    P##y1 = *reinterpret_cast<const bf16x8*>(pb1 + (size_t)(kb) * 512);       \
    P##x2 = *reinterpret_cast<const bf16x8*>(pa0 + (size_t)(kb + 1) * 512);   \
    P##x3 = *reinterpret_cast<const bf16x8*>(pa1 + (size_t)(kb + 1) * 512);   \
    P##y2 = *reinterpret_cast<const bf16x8*>(pb0 + (size_t)(kb + 1) * 512);   \
    P##y3 = *reinterpret_cast<const bf16x8*>(pb1 + (size_t)(kb + 1) * 512);   \
}
#define QSTEP(P) {                                                            \
    acc[0][0] = mfma32(P##x0, P##y0, acc[0][0]);                              \
    acc[0][1] = mfma32(P##x0, P##y1, acc[0][1]);                              \
    acc[1][0] = mfma32(P##x1, P##y0, acc[1][0]);                              \
    acc[1][1] = mfma32(P##x1, P##y1, acc[1][1]);                              \
    acc[0][0] = mfma32(P##x2, P##y2, acc[0][0]);                              \
    acc[0][1] = mfma32(P##x2, P##y3, acc[0][1]);                              \
    acc[1][0] = mfma32(P##x3, P##y2, acc[1][0]);                              \
    acc[1][1] = mfma32(P##x3, P##y3, acc[1][1]);                              \
}
__global__ __launch_bounds__(256) void gemm_qkv(
        const u16* __restrict__ Af, const u16* __restrict__ Bf,
        const float* __restrict__ bias,
        u16* __restrict__ qo, u16* __restrict__ ko2, u16* __restrict__ vTo,
        float* __restrict__ knp2, float* __restrict__ qn2) {
    __shared__ u16 st[4][2][2048];   // per-wave 2x4KB staging (epilogue only)
    int lin = blockIdx.x;
    int g = lin & 7, i2 = lin >> 3;           // i2: 0..95
    const int mblk = ((g & 3) * 8 + (i2 & 7)) * 128;
    const int nblk = ((g >> 2) * 12 + (i2 >> 3)) * 128;
    const int tid = threadIdx.x;
    const int w = tid >> 6, lane = tid & 63;
    const int la = lane & 31, hi = lane >> 5;
    const int wr = w >> 1, wc = w & 1;
    const int mt0 = (mblk >> 5) + wr * 2;
    const int nt0 = (nblk >> 5) + wc * 2;
    const u16* pa0 = Af + (size_t)mt0 * 64 * 512 + lane * 8;
    const u16* pa1 = pa0 + 64 * 512;
    const u16* pb0 = Bf + (size_t)nt0 * 64 * 512 + lane * 8;
    const u16* pb1 = pb0 + 64 * 512;
    f32x16 acc[2][2] = {};
    bf16x8 ax0, ax1, ax2, ax3, ay0, ay1, ay2, ay3;
    bf16x8 bx0, bx1, bx2, bx3, by0, by1, by2, by3;
    QLOAD(a, 0)
    #pragma unroll 4
    for (int kb = 0; kb < 64; kb += 4) {
        const int n1 = (kb + 2 < 62) ? kb + 2 : 62;
        QLOAD(b, n1)
        QSTEP(a)
        const int n2 = (kb + 4 < 62) ? kb + 4 : 62;
        QLOAD(a, n2)
        QSTEP(b)
    }
    // ---- epilogue: scatter into LDS, linear coalesced global copy, fused norms ----
    const int c0 = nblk + wc * 64;
    const int seg = c0 >> 6;                 // 0..47
    const int h = seg / 3, which = seg % 3;  // wave-uniform
    const int mrow0 = mblk + wr * 64;
    const int bb = mrow0 >> 11;
    const int bh = bb * NUM_HEADS + h;
    const int tglob0 = (mrow0 & (SEQ - 1)) >> 5;
    u16* dstbase = (which == 0 ? qo : which == 1 ? ko2 : vTo)
                 + ((size_t)(bh * 64 + tglob0)) * 2048;
    u16* myst = &st[w][0][0];
    #pragma unroll
    for (int mi = 0; mi < 2; ++mi)
    #pragma unroll
    for (int ni = 0; ni < 2; ++ni) {
        const int d = ni * 32 + la;
        const float bv = bias[c0 + ni * 32 + la];
        #pragma unroll
        for (int r = 0; r < 16; ++r) {
            const int srow = (r & 3) + 8 * (r >> 2) + 4 * hi;   // row within 32-tile
            const u16 o = f2bf(acc[mi][ni][r] + bv);
            int off;
            if (which == 2)   // v: ra from d, (ks,hf,e) from row
                off = ((d >> 5) * 2 + (srow >> 4)) * 512 + ((srow >> 3) & 1) * 256
                    + (d & 31) * 8 + (srow & 7);
            else              // q/k: (kk,hf,e) from d, ra from row
                off = (d >> 4) * 512 + ((d >> 3) & 1) * 256 + srow * 8 + (d & 7);
            myst[mi * 2048 + off] = o;
        }
    }
    asm volatile("s_waitcnt lgkmcnt(0)" ::: "memory");   // wave-local LDS drain
    #pragma unroll
    for (int i = 0; i < 8; ++i) {            // 8KB/wave, 128B/lane, fully coalesced
        const int eo = i * 512 + lane * 8;
        *reinterpret_cast<u32x4*>(dstbase + eo) =
            *reinterpret_cast<const u32x4*>(myst + eo);
    }
    // ---- fused norms: lane = (tile mi = lane>>5, row ra = lane&31) ----
    if (which <= 1) {
        const int mi2 = lane >> 5, ra = lane & 31;
        const u16* rp = myst + mi2 * 2048 + ra * 8;
        float ss = 0.f;
        #pragma unroll
        for (int kk = 0; kk < 4; ++kk)
        #pragma unroll
        for (int hf2 = 0; hf2 < 2; ++hf2) {
            bf16x8 v = *reinterpret_cast<const bf16x8*>(rp + kk * 512 + hf2 * 256);
            #pragma unroll
            for (int e = 0; e < 8; ++e) {
                float f = bf2f((u16)v[e]);
                ss = fmaf(f, f, ss);
            }
        }
        float mx = ss;                        // max within 32-lane half (same tile)
        #pragma unroll
        for (int off = 1; off <= 16; off <<= 1) mx = fmaxf(mx, __shfl_xor(mx, off));
        if (ra == 0) {                        // one atomic per tile (squared norms)
            const int tile = tglob0 + mi2;
            unsigned bits = __builtin_bit_cast(unsigned, mx);   // ss>=0: uint cmp == float cmp
            if (which == 0)
                atomicMax((unsigned*)&qn2[bh * 64 + tile], bits);
            else
                atomicMax((unsigned*)&knp2[bh * 8 + (tile >> 3)], bits);
        }
    }
}

// ---------------- Dense GEMM + bias + residual: 64x128 tile, 512 blocks (2/CU) ----------------
__global__ __launch_bounds__(256) void gemm_dense(
        const u16* __restrict__ A, const u16* __restrict__ W,
        const float* __restrict__ bias, const float* __restrict__ residual,
        float* __restrict__ out) {
    __shared__ u16 As[64 * 64];
    __shared__ u16 Bs[128 * 64];
    int lin = blockIdx.x;
    int g = lin & 7, i2 = lin >> 3;           // i2: 0..63
    const int mblk = (g * 8 + (i2 & 7)) * 64;
    const int nblk = (i2 >> 3) * 128;
    const int tid = threadIdx.x;
    const int w = tid >> 6, l = tid & 63;
    const int la = l & 31, hi = l >> 5;
    const int wr = w & 1, wc = w >> 1;
    const int kperm = (((l & 7) ^ (l >> 3)) << 3);
    const u16* gA = A + (size_t)(mblk + w * 16 + (l >> 3)) * K_DIM + kperm;
    const u16* gB = W + (size_t)(nblk + w * 32 + (l >> 3)) * K_DIM + kperm;
    const int sca = (la & 7) << 3;
    f32x16 acc2[2] = {};
    for (int kt = 0; kt < 16; ++kt) {
        const int ko = kt * 64;
        gl_lds16(gA + ko,              &As[(w * 16) * 64]);
        gl_lds16(gA + ko + 8 * K_DIM,  &As[(w * 16 + 8) * 64]);
        #pragma unroll
        for (int i = 0; i < 4; ++i)
            gl_lds16(gB + i * 8 * K_DIM + ko, &Bs[(w * 32 + i * 8) * 64]);
        asm volatile("s_waitcnt vmcnt(0)" ::: "memory");
        __syncthreads();
        const u16* pA = &As[(wr * 32 + la) * 64];
        const u16* pB = &Bs[(wc * 64 + la) * 64];
        #pragma unroll
        for (int kk = 0; kk < 4; ++kk) {
            const int co = (kk * 16 + hi * 8) ^ sca;
            bf16x8 a0 = *reinterpret_cast<const bf16x8*>(pA + co);
            bf16x8 b0 = *reinterpret_cast<const bf16x8*>(pB + co);
            bf16x8 b1 = *reinterpret_cast<const bf16x8*>(pB + 32 * 64 + co);
            acc2[0] = mfma32(a0, b0, acc2[0]);
            acc2[1] = mfma32(a0, b1, acc2[1]);
        }
        __syncthreads();
    }
    #pragma unroll
    for (int ni = 0; ni < 2; ++ni) {
        int c = nblk + wc * 64 + ni * 32 + la;
        float bv = bias[c];
        #pragma unroll
        for (int r = 0; r < 16; ++r) {
            int m = mblk + wr * 32 + (r & 3) + 8 * (r >> 2) + 4 * hi;
            out[(size_t)m * HIDDEN + c] = acc2[ni][r] + bv + residual[(size_t)m * HIDDEN + c];
        }
    }
}

// ---------------- Flash attention: dual-q-tile items (2 chains/wave) ----------------
#define LOADT(P, tt) {                                                        \
    const u16* kp_ = kbase + (size_t)(tt) * 2048;                             \
    P##k0 = *reinterpret_cast<const bf16x8*>(kp_);                            \
    P##k1 = *reinterpret_cast<const bf16x8*>(kp_ + 512);                      \
    P##k2 = *reinterpret_cast<const bf16x8*>(kp_ + 1024);                     \
    P##k3 = *reinterpret_cast<const bf16x8*>(kp_ + 1536);                     \
    const u16* vp_ = vbase + (size_t)(tt) * 2048;                             \
    P##v0 = *reinterpret_cast<const bf16x8*>(vp_);                            \
    P##v1 = *reinterpret_cast<const bf16x8*>(vp_ + 512);                      \
    P##v2 = *reinterpret_cast<const bf16x8*>(vp_ + 1024);                     \
    P##v3 = *reinterpret_cast<const bf16x8*>(vp_ + 1536);                     \
}

// softmax + PV for one side given score regs SA/SB, per-side base, accumulators
#define SMPV(SA, SB, BASEX, DIAGX, LI, OA, OB, P) {                           \
    float p_[16];                                                             \
    _Pragma("unroll")                                                         \
    for (int r = 0; r < 16; ++r) {                                            \
        const float cst_ = (float)((r & 3) + 8 * (r >> 2));                   \
        p_[r] = __builtin_amdgcn_exp2f(                                       \
            fmaf(SA[r] + SB[r], IN2, fmaf(cst_, slope2, BASEX)));             \
    }                                                                         \
    if (DIAGX) {                                                              \
        _Pragma("unroll")                                                     \
        for (int r = 0; r < 16; ++r) {                                        \
            int kr_ = (r & 3) + 8 * (r >> 2) + 4 * hi;                        \
            if (kr_ > la) p_[r] = 0.f;                                        \
        }                                                                     \
    }                                                                         \
    LI += ((p_[0] + p_[1]) + (p_[2] + p_[3])) + ((p_[4] + p_[5]) + (p_[6] + p_[7]))   \
        + ((p_[8] + p_[9]) + (p_[10] + p_[11])) + ((p_[12] + p_[13]) + (p_[14] + p_[15])); \
    unsigned pk_[8];                                                          \
    _Pragma("unroll")                                                         \
    for (int m = 0; m < 4; ++m) {                                             \
        unsigned b0_ = __builtin_bit_cast(unsigned, p_[4 * m])     + 0x8000u; \
        unsigned b1_ = __builtin_bit_cast(unsigned, p_[4 * m + 1]) + 0x8000u; \
        unsigned b2_ = __builtin_bit_cast(unsigned, p_[4 * m + 2]) + 0x8000u; \
        unsigned b3_ = __builtin_bit_cast(unsigned, p_[4 * m + 3]) + 0x8000u; \
        pk_[2 * m]     = __builtin_amdgcn_perm(b1_, b0_, 0x07060302u);        \
        pk_[2 * m + 1] = __builtin_amdgcn_perm(b3_, b2_, 0x07060302u);        \
    }                                                                         \
    u32x2 r0_ = __builtin_amdgcn_permlane32_swap(pk_[0], pk_[2], false, false); \
    u32x2 r1_ = __builtin_amdgcn_permlane32_swap(pk_[1], pk_[3], false, false); \
    u32x2 r2_ = __builtin_amdgcn_permlane32_swap(pk_[4], pk_[6], false, false); \
    u32x2 r3_ = __builtin_amdgcn_permlane32_swap(pk_[5], pk_[7], false, false); \
    u32x4 pb0_, pb1_;                                                         \
    pb0_[0] = r0_[0]; pb0_[1] = r1_[0]; pb0_[2] = r0_[1]; pb0_[3] = r1_[1];   \
    pb1_[0] = r2_[0]; pb1_[1] = r3_[0]; pb1_[2] = r2_[1]; pb1_[3] = r3_[1];   \
    bf16x8 pf0_ = __builtin_bit_cast(bf16x8, pb0_);                           \
    bf16x8 pf1_ = __builtin_bit_cast(bf16x8, pb1_);                           \
    OA = mfma32(P##v0, pf0_, OA);                                             \
    OA = mfma32(P##v1, pf1_, OA);                                             \
    OB = mfma32(P##v2, pf0_, OB);                                             \
    OB = mfma32(P##v3, pf1_, OB);                                             \
}

#define STEP2(P, N, tcur, tnxt, DIAGH, DOLO, DIAGL) {                         \
    const int k0_ = (tcur) * 32;                                              \
    f32x16 sha_ = {}, shb_ = {};                                              \
    sha_ = mfma32(P##k0, qfh0, sha_);                                         \
    shb_ = mfma32(P##k1, qfh1, shb_);                                         \
    sha_ = mfma32(P##k2, qfh2, sha_);                                         \
    shb_ = mfma32(P##k3, qfh3, shb_);                                         \
    f32x16 sla_ = {}, slb_ = {};                                              \
    if (DOLO) {                                                               \
        sla_ = mfma32(P##k0, qfl0, sla_);                                     \
        slb_ = mfma32(P##k1, qfl1, slb_);                                     \
        sla_ = mfma32(P##k2, qfl2, sla_);                                     \
        slb_ = mfma32(P##k3, qfl3, slb_);                                     \
    }                                                                         \
    LOADT(N, tnxt)                                                            \
    {                                                                         \
        const float baseh_ = fmaf(slope2, (float)(k0_ - qw_hi), C0 - kb_h);   \
        SMPV(sha_, shb_, baseh_, DIAGH, l_h, o0h, o1h, P)                     \
    }                                                                         \
    if (DOLO) {                                                               \
        const float basel_ = fmaf(slope2, (float)(k0_ - qw_lo), C0 - kb_l);   \
        SMPV(sla_, slb_, basel_, DIAGL, l_l, o0l, o1l, P)                     \
    }                                                                         \
}

__global__ __launch_bounds__(256) void attn(
        const u16* __restrict__ Qf, const u16* __restrict__ Kf,
        const u16* __restrict__ Vf, const float* __restrict__ alibi,
        const float* __restrict__ knp2, const float* __restrict__ qn2,
        u16* __restrict__ ctx, unsigned int* __restrict__ ctr) {
    __shared__ float o_l[4][64][33];
    __shared__ float ml[4][32];
    __shared__ unsigned int s_idx;
    const int grp  = blockIdx.x & 7;
    const int lst  = grp >> 1;
    const int bat  = grp & 1;
    // packed bh-head lists (byte j = head of slot j); 32 qt-pairs per slot
    const unsigned long long LH = (lst == 0) ? 0x0000000007080Full
                               : (lst == 1) ? 0x000000000006090Eull
                               : (lst == 2) ? 0x0000000003050A0Dull
                                            : 0x00000102040B0Cull;
    const unsigned nit = (lst == 0) ? 96u : (lst == 3) ? 160u : 128u;
    const int wave = __builtin_amdgcn_readfirstlane(threadIdx.x >> 6);  // SGPR
    const int lane = threadIdx.x & 63;
    const int la = lane & 31, hi = lane >> 5;

    for (;;) {
        if (threadIdx.x == 0) s_idx = atomicAdd(ctr + grp, 1u);
        __syncthreads();                     // publish s_idx; protect o_l reuse
        const unsigned int idx = s_idx;
        if (idx >= nit) return;
        const int h  = (int)((LH >> (8 * (idx >> 5))) & 0xFF);
        const int pr = (int)(idx & 31u);
        const int qt_hi = 63 - 2 * pr;       // pairs: (63,62),(61,60),...,(1,0)
        const int qt_lo = qt_hi - 1;
        const int bh = bat * 16 + h;
        const int qw_hi = qt_hi * 32;
        const int qw_lo = qw_hi - 32;
        const size_t tbh = (size_t)bh * 64;
        const float slope2 = alibi[(size_t)bh * SEQ + 1] * LOG2E;

        // Q fragments for both q-tiles
        const u16* qph = Qf + (tbh + qt_hi) * 2048 + lane * 8;
        bf16x8 qfh0 = *reinterpret_cast<const bf16x8*>(qph);
        bf16x8 qfh1 = *reinterpret_cast<const bf16x8*>(qph + 512);
        bf16x8 qfh2 = *reinterpret_cast<const bf16x8*>(qph + 1024);
        bf16x8 qfh3 = *reinterpret_cast<const bf16x8*>(qph + 1536);
        const u16* qpl = qph - 2048;
        bf16x8 qfl0 = *reinterpret_cast<const bf16x8*>(qpl);
        bf16x8 qfl1 = *reinterpret_cast<const bf16x8*>(qpl + 512);
        bf16x8 qfl2 = *reinterpret_cast<const bf16x8*>(qpl + 1024);
        bf16x8 qfl3 = *reinterpret_cast<const bf16x8*>(qpl + 1536);

        // hoisted first-tile K/V load
        const u16* kbase = Kf + tbh * 2048 + lane * 8;
        const u16* vbase = Vf + tbh * 2048 + lane * 8;
        const int t0 = qt_hi - wave;
        const int ta = (t0 >= 0) ? t0 : 0;
        bf16x8 ak0, ak1, ak2, ak3, av0, av1, av2, av3;
        bf16x8 bk0, bk1, bk2, bk3, bv0, bv1, bv2, bv3;
        LOADT(a, ta)

        // kb per side from fused squared norms (one sqrt per side)
        const float* kp8 = knp2 + bh * 8;
        const float knv2 = fmaxf(fmaxf(fmaxf(kp8[0], kp8[1]), fmaxf(kp8[2], kp8[3])),
                                 fmaxf(fmaxf(kp8[4], kp8[5]), fmaxf(kp8[6], kp8[7])));
        const float kb_h = sqrtf(qn2[tbh + qt_hi] * knv2) * IN2;
        const float kb_l = sqrtf(qn2[tbh + qt_lo] * knv2) * IN2;
        const float C0 = slope2 * (float)(4 * hi - la);

        // static windows; loop to t_min = min (extra tiles only add accurate terms)
        const float Wh = (47.f + 2.f * kb_h) / slope2;
        const float Wl = (47.f + 2.f * kb_l) / slope2;
        const int lo_kh = qw_hi - 31 - (int)Wh;
        const int lo_kl = qw_lo - 31 - (int)Wl;
        const int t_lh = lo_kh <= 0 ? 0 : ((lo_kh + 31) >> 5);
        const int t_ll = lo_kl <= 0 ? 0 : ((lo_kl + 31) >> 5);
        const int t_min = (t_lh < t_ll) ? t_lh : t_ll;

        f32x16 o0h = {}, o1h = {}, o0l = {}, o1l = {};
        float l_h = 0.f, l_l = 0.f;

        if (t0 >= t_min) {
            const int nit2 = ((t0 - t_min) >> 2) + 1;
            const int t1 = (nit2 > 1) ? t0 - 4 : t0;
            // peeled first iteration: flags by wave
            if (wave == 0)      { STEP2(a, b, t0, t1, 1, 0, 0) }   // hi diag, lo absent
            else if (wave == 1) { STEP2(a, b, t0, t1, 0, 1, 1) }   // lo diag
            else                { STEP2(a, b, t0, t1, 0, 1, 0) }
            int i = 1;
            while (i < nit2) {
                {
                    const int tc = t0 - 4 * i;
                    const int tn = (i + 1 < nit2) ? tc - 4 : tc;
                    STEP2(b, a, tc, tn, 0, 1, 0)
                }
                ++i;
                if (i >= nit2) break;
                {
                    const int tc = t0 - 4 * i;
                    const int tn = (i + 1 < nit2) ? tc - 4 : tc;
                    STEP2(a, b, tc, tn, 0, 1, 0)
                }
                ++i;
            }
        }

        const int qq = threadIdx.x >> 3;
        const int d0 = (threadIdx.x & 7) * 8;
        const int bb = bh >> 4, hh = bh & 15;

        // ---- combine HI ----
        l_h += __shfl_xor(l_h, 32);
        if (hi == 0) ml[wave][la] = l_h;
        #pragma unroll
        for (int r = 0; r < 16; ++r) {
            int d = (r & 3) + 8 * (r >> 2) + 4 * hi;
            o_l[wave][d][la]      = o0h[r];
            o_l[wave][d + 32][la] = o1h[r];
        }
        __syncthreads();
        {
            float L = ml[0][qq] + ml[1][qq] + ml[2][qq] + ml[3][qq];
            float inv = 1.0f / L;
            unsigned int packed[4];
            #pragma unroll
            for (int e2 = 0; e2 < 4; ++e2) {
                float Oa = o_l[0][d0 + 2 * e2][qq] + o_l[1][d0 + 2 * e2][qq]
                         + o_l[2][d0 + 2 * e2][qq] + o_l[3][d0 + 2 * e2][qq];
                float Ob = o_l[0][d0 + 2 * e2 + 1][qq] + o_l[1][d0 + 2 * e2 + 1][qq]
                         + o_l[2][d0 + 2 * e2 + 1][qq] + o_l[3][d0 + 2 * e2 + 1][qq];
                packed[e2] = (unsigned)f2bf(Oa * inv) | ((unsigned)f2bf(Ob * inv) << 16);
            }
            u32x4 pv; pv[0] = packed[0]; pv[1] = packed[1]; pv[2] = packed[2]; pv[3] = packed[3];
            *reinterpret_cast<u32x4*>(
                &ctx[((size_t)(bb * SEQ + qw_hi + qq)) * HIDDEN + hh * HEAD_DIM + d0]) = pv;
        }
        __syncthreads();   // all hi reads done before lo overwrites

        // ---- combine LO ----
        l_l += __shfl_xor(l_l, 32);
        if (hi == 0) ml[wave][la] = l_l;
        #pragma unroll
        for (int r = 0; r < 16; ++r) {
            int d = (r & 3) + 8 * (r >> 2) + 4 * hi;
            o_l[wave][d][la]      = o0l[r];
            o_l[wave][d + 32][la] = o1l[r];
        }
        __syncthreads();
        {
            float L = ml[0][qq] + ml[1][qq] + ml[2][qq] + ml[3][qq];
            float inv = 1.0f / L;
            unsigned int packed[4];
            #pragma unroll
            for (int e2 = 0; e2 < 4; ++e2) {
                float Oa = o_l[0][d0 + 2 * e2][qq] + o_l[1][d0 + 2 * e2][qq]
                         + o_l[2][d0 + 2 * e2][qq] + o_l[3][d0 + 2 * e2][qq];
                float Ob = o_l[0][d0 + 2 * e2 + 1][qq] + o_l[1][d0 + 2 * e2 + 1][qq]
                         + o_l[2][d0 + 2 * e2 + 1][qq] + o_l[3][d0 + 2 * e2 + 1][qq];
                packed[e2] = (unsigned)f2bf(Oa * inv) | ((unsigned)f2bf(Ob * inv) << 16);
            }
            u32x4 pv; pv[0] = packed[0]; pv[1] = packed[1]; pv[2] = packed[2]; pv[3] = packed[3];
            *reinterpret_cast<u32x4*>(
                &ctx[((size_t)(bb * SEQ + qw_lo + qq)) * HIDDEN + hh * HEAD_DIM + d0]) = pv;
        }
    }
}

extern "C" void kernel_launch(void* const* d_in, const int* in_sizes, int n_in,
                              void* d_out, int out_size, void* d_ws, size_t ws_size,
                              hipStream_t stream) {
    const float* x        = (const float*)d_in[0];
    const float* residual = (const float*)d_in[1];
    const float* alibi    = (const float*)d_in[2];
    const float* W_qkv    = (const float*)d_in[4];
    const float* b_qkv    = (const float*)d_in[5];
    const float* W_dense  = (const float*)d_in[6];
    const float* b_dense  = (const float*)d_in[7];
    float* out = (float*)d_out;

    char* ws = (char*)d_ws;
    u16* xb  = (u16*)(ws);                 //  8 MB  x bf16 fragment-major
    u16* wqb = (u16*)(ws + 8388608);       //  6 MB  W_qkv bf16 fragment-major
    u16* wdb = (u16*)(ws + 14680064);      //  2 MB  W_dense bf16 row-major
    u16* q   = (u16*)(ws + 16777216);      //  8 MB  fragment-major Q tiles
    u16* k   = (u16*)(ws + 25165824);      //  8 MB  fragment-major K tiles
    u16* vT  = (u16*)(ws + 33554432);      //  8 MB  fragment-major V tiles
    u16* ctx = (u16*)(ws + 41943040);      //  8 MB  [B*S][1024]
    float* knp2 = (float*)(ws + 50331648); //  1 KB  per-(bh,slice) max ||k||^2
    float* qn2  = (float*)(ws + 50331648 + 1024);  // 8 KB per-(bh,qt) max ||q||^2
    unsigned int* ctr = (unsigned int*)(ws + 50331648 + 16384);  // 8 group counters

    cvt_all<<<4096, 256, 0, stream>>>(x, W_qkv, W_dense, xb, wqb, wdb, knp2, ctr);
    gemm_qkv<<<768, 256, 0, stream>>>(xb, wqb, b_qkv, q, k, vT, knp2, qn2);
    attn<<<512, 256, 0, stream>>>(q, k, vT, alibi, knp2, qn2, ctx, ctr);
    gemm_dense<<<512, 256, 0, stream>>>(ctx, wdb, b_dense, residual, out);
}